// Round 4
// baseline (141.800 us; speedup 1.0000x reference)
//
#include <hip/hip_runtime.h>
#include <hip/hip_fp16.h>
#include <type_traits>

#define LQ 21760
#define MROWS 43520
#define LEN 21760

typedef __attribute__((ext_vector_type(8))) _Float16 half8;
typedef __attribute__((ext_vector_type(4))) float f32x4;

__device__ __forceinline__ uint pkh(float a, float b) {
  auto v = __builtin_amdgcn_cvt_pkrtz(a, b);
  return __builtin_bit_cast(uint, v);
}
__device__ __forceinline__ ushort h16(float x) {
  return __half_as_ushort(__float2half(x));
}
__device__ __forceinline__ float hlo(uint u) {
  return __half2float(__ushort_as_half((ushort)(u & 0xffffu)));
}
__device__ __forceinline__ float hhi(uint u) {
  return __half2float(__ushort_as_half((ushort)(u >> 16)));
}

// ushort index of the 16B slot for (row, k8) with XOR swizzle (<=2-way banks)
__device__ __forceinline__ int swz8(int row, int k8) {
  return row * 32 + ((k8 ^ (row & 3) ^ ((row >> 2) & 3)) << 3);
}

// ---- f16 MFMA GEMM body, double-buffered LDS, 1 barrier per K-step --------
// C[MR, BN] = A[MR, K=256] @ WT^T + bias. 512 thr = 8 waves.
// MR=128: waves 2M x 4N.  MR=64: waves 1M x 8N (680-block balance for out).
template <int BN, int MR, bool SPLIT, typename AT, typename OT>
__device__ __forceinline__ void gemm_body(
    const AT* __restrict__ A, int lda, const ushort* __restrict__ WT,
    const float* __restrict__ bias, const float* __restrict__ bias2,
    OT* __restrict__ Cout, int ldc, ushort* __restrict__ C2, int mblk,
    ushort* Asb, ushort* Bsb) {
  constexpr int WNW = (MR == 128) ? 4 : 8;  // waves along N
  constexpr int WN = BN / WNW;
  constexpr int NI = WN / 16;
  constexpr int BSTEP = (BN * 4) / 512;
  const int tid = threadIdx.x;
  const int m0 = mblk * MR;
  const int w = tid >> 6;
  const int wm = (MR == 128) ? (w >> 2) : 0;
  const int wn = (MR == 128) ? (w & 3) : w;
  const int l = tid & 63, lr = l & 15, lk = l >> 4;
  const int arow = tid >> 2, ak8 = tid & 3;

  f32x4 acc[4][NI];
#pragma unroll
  for (int mi = 0; mi < 4; ++mi)
#pragma unroll
    for (int ni = 0; ni < NI; ++ni) acc[mi][ni] = {0.f, 0.f, 0.f, 0.f};

  float4 aF0, aF1;
  uint4 aR;
  uint4 bR[BSTEP];

  auto loadA = [&](int k0) {
    if (MR == 64 && tid >= 256) return;  // 64 rows x 4 slots = 256 loaders
    const AT* src = A + (size_t)(m0 + arow) * lda + k0 + ak8 * 8;
    if constexpr (std::is_same_v<AT, float>) {
      aF0 = *(const float4*)src;
      aF1 = *(const float4*)(src + 4);
    } else {
      aR = *(const uint4*)src;
    }
  };
  auto loadB = [&](int k0) {
#pragma unroll
    for (int i = 0; i < BSTEP; ++i) {
      int s = tid + i * 512;
      bR[i] = *(const uint4*)(WT + (size_t)(s >> 2) * 256 + k0 + (s & 3) * 8);
    }
  };
  auto writeLDS = [&](int cur) {
    ushort* Ab = Asb + cur * (MR * 32);
    ushort* Bb = Bsb + cur * (BN * 32);
    if (!(MR == 64 && tid >= 256)) {
      uint4 pk;
      if constexpr (std::is_same_v<AT, float>)
        pk = make_uint4(pkh(aF0.x, aF0.y), pkh(aF0.z, aF0.w),
                        pkh(aF1.x, aF1.y), pkh(aF1.z, aF1.w));
      else
        pk = aR;
      *(uint4*)&Ab[swz8(arow, ak8)] = pk;
    }
#pragma unroll
    for (int i = 0; i < BSTEP; ++i) {
      int s = tid + i * 512;
      *(uint4*)&Bb[swz8(s >> 2, s & 3)] = bR[i];
    }
  };

  loadA(0);
  loadB(0);
#pragma unroll
  for (int ks = 0; ks < 8; ++ks) {
    const int cur = ks & 1;
    writeLDS(cur);
    __syncthreads();
    if (ks < 7) {  // prefetch AFTER barrier: overlaps ds_read + MFMA below
      loadA((ks + 1) * 32);
      loadB((ks + 1) * 32);
    }
    const ushort* Ab = Asb + cur * (MR * 32);
    const ushort* Bb = Bsb + cur * (BN * 32);
    half8 af[4], bfr[NI];
#pragma unroll
    for (int mi = 0; mi < 4; ++mi)
      af[mi] = *(const half8*)&Ab[swz8(wm * 64 + mi * 16 + lr, lk)];
#pragma unroll
    for (int ni = 0; ni < NI; ++ni)
      bfr[ni] = *(const half8*)&Bb[swz8(wn * WN + ni * 16 + lr, lk)];
#pragma unroll
    for (int mi = 0; mi < 4; ++mi)
#pragma unroll
      for (int ni = 0; ni < NI; ++ni)
        acc[mi][ni] = __builtin_amdgcn_mfma_f32_16x16x32_f16(
            af[mi], bfr[ni], acc[mi][ni], 0, 0, 0);
  }
#pragma unroll
  for (int mi = 0; mi < 4; ++mi) {
#pragma unroll
    for (int ni = 0; ni < NI; ++ni) {
      int col = wn * WN + ni * 16 + lr;
      float bs;
      if constexpr (SPLIT)
        bs = (col < 256) ? bias[col] : bias2[col - 256];
      else
        bs = bias[col];
      int row = m0 + wm * 64 + mi * 16 + lk * 4;
#pragma unroll
      for (int r = 0; r < 4; ++r) {
        float v = acc[mi][ni][r] + bs;
        if constexpr (SPLIT) {
          if (col < 256)
            ((ushort*)Cout)[(size_t)(row + r) * 256 + col] = h16(v);
          else
            C2[(size_t)(row + r) * 128 + col - 256] = h16(v);
        } else if constexpr (std::is_same_v<OT, ushort>) {
          Cout[(size_t)(row + r) * ldc + col] = h16(v);
        } else {
          Cout[(size_t)(row + r) * ldc + col] = v;
        }
      }
    }
  }
}

// ---- front: blocks 0..339 -> value GEMM, 340..679 -> offsets+logits GEMM ---
__global__ __launch_bounds__(512) void gemm_front(
    const float* __restrict__ inpf, const ushort* __restrict__ WTv,
    const float* __restrict__ bval, ushort* __restrict__ value16,
    const float* __restrict__ query, const ushort* __restrict__ WTol,
    const float* __restrict__ boff, const float* __restrict__ battn,
    ushort* __restrict__ off16, ushort* __restrict__ logit16) {
  __shared__ ushort Asb[2 * 128 * 32];
  __shared__ ushort Bsb[2 * 384 * 32];
  int bid = blockIdx.x;
  if (bid < 340) {
    gemm_body<256, 128, false, float, ushort>(inpf, 256, WTv, bval, nullptr,
                                              value16, 256, nullptr, bid, Asb,
                                              Bsb);
  } else {
    gemm_body<384, 128, true, float, ushort>(query, 256, WTol, boff, battn,
                                             off16, 256, logit16, bid - 340,
                                             Asb, Bsb);
  }
}

// 64-row tiles -> 680 blocks (340 was 1.33 blocks/CU: 2-round quantized tail)
__global__ __launch_bounds__(512) void gemm_out(
    const ushort* __restrict__ midb, const ushort* __restrict__ WTu,
    const float* __restrict__ bout, float* __restrict__ outp) {
  __shared__ ushort Asb[2 * 64 * 32];
  __shared__ ushort Bsb[2 * 256 * 32];
  gemm_body<256, 64, false, ushort, float>(midb, 512, WTu, bout, nullptr, outp,
                                           256, nullptr, blockIdx.x, Asb, Bsb);
}

// -------- prep: all weight transposes (f32 [K][N] -> f16 [N][256]) ----------
__global__ __launch_bounds__(256) void wt_cvt_all(
    const float* __restrict__ Wval, const float* __restrict__ Woff,
    const float* __restrict__ Wattn, const float* __restrict__ Wout,
    ushort* __restrict__ WTv, ushort* __restrict__ WTol,
    ushort* __restrict__ WTu) {
  int i = blockIdx.x * 256 + threadIdx.x;  // < 229376
  if (i < 65536) {
    int n = i >> 8, k = i & 255;
    WTv[i] = h16(Wval[(size_t)k * 256 + n]);
  } else if (i < 163840) {
    int j = i - 65536;
    int n = j >> 8, k = j & 255;
    float s = (n < 256) ? Woff[(size_t)k * 256 + n] : Wattn[(size_t)k * 128 + n - 256];
    WTol[j] = h16(s);
  } else {
    int j = i - 163840;
    int n = j >> 8, k = j & 255;
    WTu[j] = h16(Wout[(size_t)k * 256 + n]);
  }
}

// ------------- sampler: XCD-pinned (batch, head-pair) groups ----------------
// block = 256 thr; grp = blockIdx&7 -> (batch, head-pair); 32 queries/block.
// Gather order is LEVEL-MAJOR block-wide (lvl 3 -> 0): levels 3/2 have tiny
// footprints (16/64 KB per head-pair) with ~4x intra-block touch reuse; the
// old per-group rotation interleaved levels so stream traffic from lvl 0/1
// evicted them between touches. Slot stagger switched additive -> XOR
// (slot = lp ^ group) so simultaneous same-level reads stay <=2-way banked.
__global__ __launch_bounds__(256) void msda_sample(
    const ushort* __restrict__ off16,   // [M][256] f16
    const ushort* __restrict__ logit16, // [M][128] f16
    const float* __restrict__ refpts,   // [M][4][2]
    const ushort* __restrict__ value,   // [B][LEN][256] f16
    ushort* __restrict__ midb) {        // f16, row r at midb + r*512
  __shared__ float prs[64][16];   // 4 KB
  __shared__ float refs[32][4][2];
  __shared__ int tix[1024][4];    // 16 KB
  __shared__ uint twp[1024][2];   // 8 KB

  const int bid = blockIdx.x;
  const int grp = bid & 7;        // -> XCD (round-robin dispatch assumption)
  const int sub = bid >> 3;       // 0..679
  const int b = grp >> 2;
  const int hp = grp & 3;         // head pair: heads 2hp, 2hp+1
  const int q0 = sub * 32;
  const int tid = threadIdx.x;
  const size_t fqB = (size_t)b * LQ + q0;

  // ---- A0: refs (32q x 8 vals, 1/thread) + softmax for 64 (q, h') pairs ----
  {
    int q = tid >> 3, r = tid & 7;
    refs[q][r >> 1][r & 1] = refpts[(fqB + q) * 8 + r];
  }
  if (tid < 64) {
    int q = tid >> 1, hh = tid & 1;
    int h = hp * 2 + hh;
    const uint4* lp = (const uint4*)(logit16 + (fqB + q) * 128 + h * 16);
    uint4 p0 = lp[0], p1 = lp[1];
    float v[16] = {hlo(p0.x), hhi(p0.x), hlo(p0.y), hhi(p0.y),
                   hlo(p0.z), hhi(p0.z), hlo(p0.w), hhi(p0.w),
                   hlo(p1.x), hhi(p1.x), hlo(p1.y), hhi(p1.y),
                   hlo(p1.z), hhi(p1.z), hlo(p1.w), hhi(p1.w)};
    float m = v[0];
#pragma unroll
    for (int i = 1; i < 16; ++i) m = fmaxf(m, v[i]);
    float s = 0.f;
#pragma unroll
    for (int i = 0; i < 16; ++i) { v[i] = __expf(v[i] - m); s += v[i]; }
    float inv = 1.0f / s;
#pragma unroll
    for (int i = 0; i < 16; ++i) prs[tid][i] = v[i] * inv;
  }
  __syncthreads();

  // ---- A2: 1024 tasks (q 0..31, h' 0..1, lp 0..15), 4 per thread ----
#pragma unroll
  for (int i = 0; i < 4; ++i) {
    int t = tid + i * 256;
    int q = t >> 5;
    int hh = (t >> 4) & 1;
    int lp_ = t & 15;
    int lvl = lp_ >> 2;
    int h = hp * 2 + hh;
    uint op = ((const uint*)off16)[(fqB + q) * 128 + h * 16 + lp_];
    float ox = hlo(op), oy = hhi(op);
    float aw = prs[q * 2 + hh][lp_];
    float rx = refs[q][lvl][0], ry = refs[q][lvl][1];
    int Wl = 128 >> lvl;
    int st = (lvl == 0) ? 0 : ((lvl == 1) ? 16384 : ((lvl == 2) ? 20480 : 21504));
    float fW = (float)Wl;
    float invW = 1.0f / fW;
    float x = (rx + ox * invW) * fW - 0.5f;
    float y = (ry + oy * invW) * fW - 0.5f;
    float x0f = floorf(x), y0f = floorf(y);
    float wx1 = x - x0f, wy1 = y - y0f;
    float wx0 = 1.f - wx1, wy0 = 1.f - wy1;
    int x0 = (int)x0f, y0 = (int)y0f;
    int x1 = x0 + 1, y1 = y0 + 1;
    bool vx0 = (x0 >= 0) & (x0 < Wl), vx1 = (x1 >= 0) & (x1 < Wl);
    bool vy0 = (y0 >= 0) & (y0 < Wl), vy1 = (y1 >= 0) & (y1 < Wl);
    int xc0 = min(max(x0, 0), Wl - 1), xc1 = min(max(x1, 0), Wl - 1);
    int yc0 = min(max(y0, 0), Wl - 1), yc1 = min(max(y1, 0), Wl - 1);
    int base = st * 256 + h * 32;
    int g16 = t >> 4;
    int slot = (t & ~15) | ((lp_ ^ g16) & 15);   // XOR stagger
    float w00 = (vx0 && vy0) ? wx0 * wy0 * aw : 0.f;
    float w10 = (vx1 && vy0) ? wx1 * wy0 * aw : 0.f;
    float w01 = (vx0 && vy1) ? wx0 * wy1 * aw : 0.f;
    float w11 = (vx1 && vy1) ? wx1 * wy1 * aw : 0.f;
    tix[slot][0] = base + (yc0 * Wl + xc0) * 256;
    tix[slot][1] = base + (yc0 * Wl + xc1) * 256;
    tix[slot][2] = base + (yc1 * Wl + xc0) * 256;
    tix[slot][3] = base + (yc1 * Wl + xc1) * 256;
    twp[slot][0] = pkh(w00, w10);
    twp[slot][1] = pkh(w01, w11);
  }
  __syncthreads();

  // ---- B: gather. 4 lanes per (q,h'); lane owns 8 dims (16B f16 loads) ----
  const int g = tid >> 2;
  const int dl = tid & 3;
  const ushort* vb = value + (size_t)b * LEN * 256 + dl * 8;
  float a0 = 0.f, a1 = 0.f, a2 = 0.f, a3 = 0.f;
  float a4 = 0.f, a5 = 0.f, a6 = 0.f, a7 = 0.f;
  uint c0 = 0u, c1 = 0u, c2 = 0u, c3 = 0u;  // f16x2 chunk accumulators
  const int tb = g * 16;

// packed f16 FMA; OS/OSH broadcast one half of the weight reg to both lanes:
//   weight = lo(WP): OS="0" OSH="0";  weight = hi(WP): OS="1" OSH="1"
#define PKC(ACC, U, WP, OS, OSH)                                        \
  asm("v_pk_fma_f16 %0, %1, %2, %0 op_sel:[0," OS ",0] op_sel_hi:[1," OSH \
      ",1]"                                                             \
      : "+v"(ACC)                                                       \
      : "v"(U), "v"(WP))
#define CORNER(U, WPW, OS, OSH)                                         \
  PKC(c0, (U).x, WPW, OS, OSH);                                         \
  PKC(c1, (U).y, WPW, OS, OSH);                                         \
  PKC(c2, (U).z, WPW, OS, OSH);                                         \
  PKC(c3, (U).w, WPW, OS, OSH)
// promote f16x2 chunk into two f32 accumulators, then reset chunk
#define PROMO1(ALO, AHI, C)                                             \
  asm("v_fma_mix_f32 %0, 1.0, %1, %0 op_sel:[0,0,0] op_sel_hi:[0,1,0]"  \
      : "+v"(ALO) : "v"(C));                                            \
  asm("v_fma_mix_f32 %0, 1.0, %1, %0 op_sel:[0,1,0] op_sel_hi:[0,1,0]"  \
      : "+v"(AHI) : "v"(C));                                            \
  C = 0u;

  // level-major order (lvl3 first: smallest footprint, highest L1 reuse)
  static constexpr int ORD[16] = {12, 13, 14, 15, 8, 9, 10, 11,
                                  4,  5,  6,  7,  0, 1, 2,  3};
#pragma unroll
  for (int t = 0; t < 16; ++t) {
    int slot = tb + ((ORD[t] ^ g) & 15);
    int4 ix = *(const int4*)&tix[slot][0];
    uint2 wp = *(const uint2*)&twp[slot][0];
    uint4 u0 = *(const uint4*)(vb + ix.x);
    uint4 u1 = *(const uint4*)(vb + ix.y);
    uint4 u2 = *(const uint4*)(vb + ix.z);
    uint4 u3 = *(const uint4*)(vb + ix.w);
    CORNER(u0, wp.x, "0", "0");
    CORNER(u1, wp.x, "1", "1");
    CORNER(u2, wp.y, "0", "0");
    CORNER(u3, wp.y, "1", "1");
    if ((t & 1) == 1) {  // promote every 2 tasks (8 corners) -> f32
      PROMO1(a0, a1, c0);
      PROMO1(a2, a3, c1);
      PROMO1(a4, a5, c2);
      PROMO1(a6, a7, c3);
    }
  }
#undef PROMO1
#undef CORNER
#undef PKC

  const int q = g >> 1, h = hp * 2 + (g & 1);
  ushort* mp = midb + (fqB + q) * 512 + h * 32 + dl * 8;
  *(uint4*)mp = make_uint4(pkh(a0, a1), pkh(a2, a3), pkh(a4, a5), pkh(a6, a7));
}

extern "C" void kernel_launch(void* const* d_in, const int* in_sizes, int n_in,
                              void* d_out, int out_size, void* d_ws,
                              size_t ws_size, hipStream_t stream) {
  (void)in_sizes; (void)n_in; (void)out_size; (void)ws_size;
  const float* query = (const float*)d_in[0];
  const float* refp  = (const float*)d_in[1];
  const float* inpf  = (const float*)d_in[2];
  const float* Woff  = (const float*)d_in[5];
  const float* boff  = (const float*)d_in[6];
  const float* Wattn = (const float*)d_in[7];
  const float* battn = (const float*)d_in[8];
  const float* Wval  = (const float*)d_in[9];
  const float* bval  = (const float*)d_in[10];
  const float* Wout  = (const float*)d_in[11];
  const float* bout  = (const float*)d_in[12];

  // ws: value16 22.3MB | off16 22.3MB | logit16 11.1MB | WT f16 ~0.45MB
  ushort* value16 = (ushort*)d_ws;
  ushort* off16   = value16 + (size_t)MROWS * 256;
  ushort* logit16 = off16 + (size_t)MROWS * 256;
  ushort* WTv     = logit16 + (size_t)MROWS * 128;
  ushort* WTol    = WTv + 65536;   // [384][256]
  ushort* WTu     = WTol + 98304;

  ushort* midb = (ushort*)d_out;   // mid f16 in-place per row (stride 512)

  wt_cvt_all<<<896, 256, 0, stream>>>(Wval, Woff, Wattn, Wout, WTv, WTol, WTu);

  gemm_front<<<680, 512, 0, stream>>>(inpf, WTv, bval, value16, query, WTol,
                                      boff, battn, off16, logit16);

  msda_sample<<<MROWS / 8, 256, 0, stream>>>(off16, logit16, refp, value16,
                                             midb);

  gemm_out<<<MROWS / 64, 512, 0, stream>>>(midb, WTu, bout, (float*)d_out);
}

// Round 5
// 140.624 us; speedup vs baseline: 1.0084x; 1.0084x over previous
//
#include <hip/hip_runtime.h>
#include <hip/hip_fp16.h>
#include <type_traits>

#define LQ 21760
#define MROWS 43520
#define LEN 21760

typedef __attribute__((ext_vector_type(8))) _Float16 half8;
typedef __attribute__((ext_vector_type(4))) float f32x4;

__device__ __forceinline__ uint pkh(float a, float b) {
  auto v = __builtin_amdgcn_cvt_pkrtz(a, b);
  return __builtin_bit_cast(uint, v);
}
__device__ __forceinline__ ushort h16(float x) {
  return __half_as_ushort(__float2half(x));
}
__device__ __forceinline__ float hlo(uint u) {
  return __half2float(__ushort_as_half((ushort)(u & 0xffffu)));
}
__device__ __forceinline__ float hhi(uint u) {
  return __half2float(__ushort_as_half((ushort)(u >> 16)));
}

// ushort index of the 16B slot for (row, k8) with XOR swizzle (<=2-way banks)
__device__ __forceinline__ int swz8(int row, int k8) {
  return row * 32 + ((k8 ^ (row & 3) ^ ((row >> 2) & 3)) << 3);
}

// ---- f16 MFMA GEMM body, double-buffered LDS, 1 barrier per K-step --------
// C[128, BN] = A[128, K=256] @ WT^T + bias. 512 thr = 8 waves (2M x 4N).
template <int BN, bool SPLIT, typename AT, typename OT>
__device__ __forceinline__ void gemm_body(
    const AT* __restrict__ A, int lda, const ushort* __restrict__ WT,
    const float* __restrict__ bias, const float* __restrict__ bias2,
    OT* __restrict__ Cout, int ldc, ushort* __restrict__ C2, int mblk,
    ushort* Asb, ushort* Bsb) {
  constexpr int WN = BN / 4;
  constexpr int NI = WN / 16;
  constexpr int BSTEP = (BN * 4) / 512;
  const int tid = threadIdx.x;
  const int m0 = mblk * 128;
  const int w = tid >> 6, wm = w >> 2, wn = w & 3;
  const int l = tid & 63, lr = l & 15, lk = l >> 4;
  const int arow = tid >> 2, ak8 = tid & 3;

  f32x4 acc[4][NI];
#pragma unroll
  for (int mi = 0; mi < 4; ++mi)
#pragma unroll
    for (int ni = 0; ni < NI; ++ni) acc[mi][ni] = {0.f, 0.f, 0.f, 0.f};

  float4 aF0, aF1;
  uint4 aR;
  uint4 bR[BSTEP];

  auto loadA = [&](int k0) {
    const AT* src = A + (size_t)(m0 + arow) * lda + k0 + ak8 * 8;
    if constexpr (std::is_same_v<AT, float>) {
      aF0 = *(const float4*)src;
      aF1 = *(const float4*)(src + 4);
    } else {
      aR = *(const uint4*)src;
    }
  };
  auto loadB = [&](int k0) {
#pragma unroll
    for (int i = 0; i < BSTEP; ++i) {
      int s = tid + i * 512;
      bR[i] = *(const uint4*)(WT + (size_t)(s >> 2) * 256 + k0 + (s & 3) * 8);
    }
  };
  auto writeLDS = [&](int cur) {
    ushort* Ab = Asb + cur * (128 * 32);
    ushort* Bb = Bsb + cur * (BN * 32);
    uint4 pk;
    if constexpr (std::is_same_v<AT, float>)
      pk = make_uint4(pkh(aF0.x, aF0.y), pkh(aF0.z, aF0.w),
                      pkh(aF1.x, aF1.y), pkh(aF1.z, aF1.w));
    else
      pk = aR;
    *(uint4*)&Ab[swz8(arow, ak8)] = pk;
#pragma unroll
    for (int i = 0; i < BSTEP; ++i) {
      int s = tid + i * 512;
      *(uint4*)&Bb[swz8(s >> 2, s & 3)] = bR[i];
    }
  };

  loadA(0);
  loadB(0);
#pragma unroll
  for (int ks = 0; ks < 8; ++ks) {
    const int cur = ks & 1;
    writeLDS(cur);
    __syncthreads();
    if (ks < 7) {  // prefetch AFTER barrier: overlaps ds_read + MFMA below
      loadA((ks + 1) * 32);
      loadB((ks + 1) * 32);
    }
    const ushort* Ab = Asb + cur * (128 * 32);
    const ushort* Bb = Bsb + cur * (BN * 32);
    half8 af[4], bfr[NI];
#pragma unroll
    for (int mi = 0; mi < 4; ++mi)
      af[mi] = *(const half8*)&Ab[swz8(wm * 64 + mi * 16 + lr, lk)];
#pragma unroll
    for (int ni = 0; ni < NI; ++ni)
      bfr[ni] = *(const half8*)&Bb[swz8(wn * WN + ni * 16 + lr, lk)];
#pragma unroll
    for (int mi = 0; mi < 4; ++mi)
#pragma unroll
      for (int ni = 0; ni < NI; ++ni)
        acc[mi][ni] = __builtin_amdgcn_mfma_f32_16x16x32_f16(
            af[mi], bfr[ni], acc[mi][ni], 0, 0, 0);
  }
#pragma unroll
  for (int mi = 0; mi < 4; ++mi) {
#pragma unroll
    for (int ni = 0; ni < NI; ++ni) {
      int col = wn * WN + ni * 16 + lr;
      float bs;
      if constexpr (SPLIT)
        bs = (col < 256) ? bias[col] : bias2[col - 256];
      else
        bs = bias[col];
      int row = m0 + wm * 64 + mi * 16 + lk * 4;
#pragma unroll
      for (int r = 0; r < 4; ++r) {
        float v = acc[mi][ni][r] + bs;
        if constexpr (SPLIT) {
          if (col < 256)
            ((ushort*)Cout)[(size_t)(row + r) * 256 + col] = h16(v);
          else
            C2[(size_t)(row + r) * 128 + col - 256] = h16(v);
        } else if constexpr (std::is_same_v<OT, ushort>) {
          Cout[(size_t)(row + r) * ldc + col] = h16(v);
        } else {
          Cout[(size_t)(row + r) * ldc + col] = v;
        }
      }
    }
  }
}

// ---- front: blocks 0..339 -> value GEMM, 340..679 -> offsets+logits GEMM ---
__global__ __launch_bounds__(512) void gemm_front(
    const float* __restrict__ inpf, const ushort* __restrict__ WTv,
    const float* __restrict__ bval, ushort* __restrict__ value16,
    const float* __restrict__ query, const ushort* __restrict__ WTol,
    const float* __restrict__ boff, const float* __restrict__ battn,
    ushort* __restrict__ off16, ushort* __restrict__ logit16) {
  __shared__ ushort Asb[2 * 128 * 32];
  __shared__ ushort Bsb[2 * 384 * 32];
  int bid = blockIdx.x;
  if (bid < 340) {
    gemm_body<256, false, float, ushort>(inpf, 256, WTv, bval, nullptr,
                                         value16, 256, nullptr, bid, Asb, Bsb);
  } else {
    gemm_body<384, true, float, ushort>(query, 256, WTol, boff, battn, off16,
                                        256, logit16, bid - 340, Asb, Bsb);
  }
}

__global__ __launch_bounds__(512) void gemm_out(
    const ushort* __restrict__ midb, const ushort* __restrict__ WTu,
    const float* __restrict__ bout, float* __restrict__ outp) {
  __shared__ ushort Asb[2 * 128 * 32];
  __shared__ ushort Bsb[2 * 256 * 32];
  gemm_body<256, false, ushort, float>(midb, 512, WTu, bout, nullptr, outp,
                                       256, nullptr, blockIdx.x, Asb, Bsb);
}

// -------- prep: all weight transposes (f32 [K][N] -> f16 [N][256]) ----------
__global__ __launch_bounds__(256) void wt_cvt_all(
    const float* __restrict__ Wval, const float* __restrict__ Woff,
    const float* __restrict__ Wattn, const float* __restrict__ Wout,
    ushort* __restrict__ WTv, ushort* __restrict__ WTol,
    ushort* __restrict__ WTu) {
  int i = blockIdx.x * 256 + threadIdx.x;  // < 229376
  if (i < 65536) {
    int n = i >> 8, k = i & 255;
    WTv[i] = h16(Wval[(size_t)k * 256 + n]);
  } else if (i < 163840) {
    int j = i - 65536;
    int n = j >> 8, k = j & 255;
    float s = (n < 256) ? Woff[(size_t)k * 256 + n] : Wattn[(size_t)k * 128 + n - 256];
    WTol[j] = h16(s);
  } else {
    int j = i - 163840;
    int n = j >> 8, k = j & 255;
    WTu[j] = h16(Wout[(size_t)k * 256 + n]);
  }
}

// ------------- sampler: XCD-pinned (batch, head-pair) groups ----------------
// block = 256 thr; grp = blockIdx&7 -> (batch, head-pair); 32 queries/block.
// Occupancy experiment (clean, single-variable): 16B task records shrink LDS
// 29,696 -> 21,504 B => 5 -> 7 blocks/CU. Gather-loop structure stays the
// simple round-0 form (explicit SW pipelines get re-serialized by the
// scheduler: rounds 1-2). pk_fma accumulation kept (round 3: -10% VALU).
// Record: {corner00 byte-off (incl head/level), dxB|dyB (disjoint bits:
// dxB in {0,512}, dyB in {0, Wl*512} >= 8192), w00w10, w01w11}.
__global__ __launch_bounds__(256) void msda_sample(
    const ushort* __restrict__ off16,   // [M][256] f16
    const ushort* __restrict__ logit16, // [M][128] f16
    const float* __restrict__ refpts,   // [M][4][2]
    const ushort* __restrict__ value,   // [B][LEN][256] f16
    ushort* __restrict__ midb) {        // f16, row r at midb + r*512
  __shared__ float prs[64][16];        // 4 KB
  __shared__ float refs[32][4][2];     // 1 KB
  __shared__ uint4 trec[1024];         // 16 KB

  const int bid = blockIdx.x;
  const int grp = bid & 7;        // -> XCD (round-robin dispatch assumption)
  const int sub = bid >> 3;       // 0..679
  const int b = grp >> 2;
  const int hp = grp & 3;         // head pair: heads 2hp, 2hp+1
  const int q0 = sub * 32;
  const int tid = threadIdx.x;
  const size_t fqB = (size_t)b * LQ + q0;

  // ---- A0: refs (32q x 8 vals, 1/thread) + softmax for 64 (q, h') pairs ----
  {
    int q = tid >> 3, r = tid & 7;
    refs[q][r >> 1][r & 1] = refpts[(fqB + q) * 8 + r];
  }
  if (tid < 64) {
    int q = tid >> 1, hh = tid & 1;
    int h = hp * 2 + hh;
    const uint4* lp = (const uint4*)(logit16 + (fqB + q) * 128 + h * 16);
    uint4 p0 = lp[0], p1 = lp[1];
    float v[16] = {hlo(p0.x), hhi(p0.x), hlo(p0.y), hhi(p0.y),
                   hlo(p0.z), hhi(p0.z), hlo(p0.w), hhi(p0.w),
                   hlo(p1.x), hhi(p1.x), hlo(p1.y), hhi(p1.y),
                   hlo(p1.z), hhi(p1.z), hlo(p1.w), hhi(p1.w)};
    float m = v[0];
#pragma unroll
    for (int i = 1; i < 16; ++i) m = fmaxf(m, v[i]);
    float s = 0.f;
#pragma unroll
    for (int i = 0; i < 16; ++i) { v[i] = __expf(v[i] - m); s += v[i]; }
    float inv = 1.0f / s;
#pragma unroll
    for (int i = 0; i < 16; ++i) prs[tid][i] = v[i] * inv;
  }
  __syncthreads();

  // ---- A2: 1024 tasks (q 0..31, h' 0..1, lp 0..15), 4 per thread ----
#pragma unroll
  for (int i = 0; i < 4; ++i) {
    int t = tid + i * 256;
    int q = t >> 5;
    int hh = (t >> 4) & 1;
    int lp_ = t & 15;
    int lvl = lp_ >> 2;
    int h = hp * 2 + hh;
    uint op = ((const uint*)off16)[(fqB + q) * 128 + h * 16 + lp_];
    float ox = hlo(op), oy = hhi(op);
    float aw = prs[q * 2 + hh][lp_];
    float rx = refs[q][lvl][0], ry = refs[q][lvl][1];
    int Wl = 128 >> lvl;
    int st = (lvl == 0) ? 0 : ((lvl == 1) ? 16384 : ((lvl == 2) ? 20480 : 21504));
    float fW = (float)Wl;
    float invW = 1.0f / fW;
    float x = (rx + ox * invW) * fW - 0.5f;
    float y = (ry + oy * invW) * fW - 0.5f;
    float x0f = floorf(x), y0f = floorf(y);
    float wx1 = x - x0f, wy1 = y - y0f;
    float wx0 = 1.f - wx1, wy0 = 1.f - wy1;
    int x0 = (int)x0f, y0 = (int)y0f;
    int x1 = x0 + 1, y1 = y0 + 1;
    bool vx0 = (x0 >= 0) & (x0 < Wl), vx1 = (x1 >= 0) & (x1 < Wl);
    bool vy0 = (y0 >= 0) & (y0 < Wl), vy1 = (y1 >= 0) & (y1 < Wl);
    int xc0 = min(max(x0, 0), Wl - 1), xc1 = min(max(x1, 0), Wl - 1);
    int yc0 = min(max(y0, 0), Wl - 1), yc1 = min(max(y1, 0), Wl - 1);
    int g16 = t >> 4;
    int slot = (t & ~15) | ((t + g16) & 15);
    float w00 = (vx0 && vy0) ? wx0 * wy0 * aw : 0.f;
    float w10 = (vx1 && vy0) ? wx1 * wy0 * aw : 0.f;
    float w01 = (vx0 && vy1) ? wx0 * wy1 * aw : 0.f;
    float w11 = (vx1 && vy1) ? wx1 * wy1 * aw : 0.f;
    // byte offset of corner (yc0, xc0) for this head/level (ushort elems x2)
    uint ixB = (uint)((((st + yc0 * Wl + xc0) * 256) + h * 32) * 2);
    // dxB in {0, 512}; dyB in {0, Wl*512 >= 8192} -- disjoint bit ranges
    uint dxy = (uint)((xc1 - xc0) * 512) | (uint)((yc1 - yc0) * Wl * 512);
    trec[slot] = make_uint4(ixB, dxy, pkh(w00, w10), pkh(w01, w11));
  }
  __syncthreads();

  // ---- B: gather. 4 lanes per (q,h'); lane owns 8 dims (16B f16 loads) ----
  const int g = tid >> 2;
  const int dl = tid & 3;
  const uint dlB = (uint)dl * 16u;
  const char* vb0c = (const char*)(value + (size_t)b * (LEN * 256));
  float a0 = 0.f, a1 = 0.f, a2 = 0.f, a3 = 0.f;
  float a4 = 0.f, a5 = 0.f, a6 = 0.f, a7 = 0.f;
  uint c0 = 0u, c1 = 0u, c2 = 0u, c3 = 0u;  // f16x2 chunk accumulators
  const int tb = g * 16;

// packed f16 FMA; OS/OSH broadcast one half of the weight reg to both lanes:
//   weight = lo(WP): OS="0" OSH="0";  weight = hi(WP): OS="1" OSH="1"
#define PKC(ACC, U, WP, OS, OSH)                                        \
  asm("v_pk_fma_f16 %0, %1, %2, %0 op_sel:[0," OS ",0] op_sel_hi:[1," OSH \
      ",1]"                                                             \
      : "+v"(ACC)                                                       \
      : "v"(U), "v"(WP))
#define CORNER(U, WPW, OS, OSH)                                         \
  PKC(c0, (U).x, WPW, OS, OSH);                                         \
  PKC(c1, (U).y, WPW, OS, OSH);                                         \
  PKC(c2, (U).z, WPW, OS, OSH);                                         \
  PKC(c3, (U).w, WPW, OS, OSH)
// promote f16x2 chunk into two f32 accumulators, then reset chunk
#define PROMO1(ALO, AHI, C)                                             \
  asm("v_fma_mix_f32 %0, 1.0, %1, %0 op_sel:[0,0,0] op_sel_hi:[0,1,0]"  \
      : "+v"(ALO) : "v"(C));                                            \
  asm("v_fma_mix_f32 %0, 1.0, %1, %0 op_sel:[0,1,0] op_sel_hi:[0,1,0]"  \
      : "+v"(AHI) : "v"(C));                                            \
  C = 0u;

#pragma unroll 4
  for (int t = 0; t < 16; ++t) {
    int slot = tb + ((t + g) & 15);
    uint4 r = trec[slot];
    uint dx_ = r.y & 0x3ffu;
    uint dy_ = r.y - dx_;
    uint o0 = r.x + dlB;
    uint o2 = o0 + dy_;
    uint4 u0 = *(const uint4*)(vb0c + o0);
    uint4 u1 = *(const uint4*)(vb0c + (o0 + dx_));
    uint4 u2 = *(const uint4*)(vb0c + o2);
    uint4 u3 = *(const uint4*)(vb0c + (o2 + dx_));
    CORNER(u0, r.z, "0", "0");
    CORNER(u1, r.z, "1", "1");
    CORNER(u2, r.w, "0", "0");
    CORNER(u3, r.w, "1", "1");
    if ((t & 1) == 1) {  // promote every 2 tasks (8 corners) -> f32
      PROMO1(a0, a1, c0);
      PROMO1(a2, a3, c1);
      PROMO1(a4, a5, c2);
      PROMO1(a6, a7, c3);
    }
  }
#undef PROMO1
#undef CORNER
#undef PKC

  const int q = g >> 1, h = hp * 2 + (g & 1);
  ushort* mp = midb + (fqB + q) * 512 + h * 32 + dl * 8;
  *(uint4*)mp = make_uint4(pkh(a0, a1), pkh(a2, a3), pkh(a4, a5), pkh(a6, a7));
}

extern "C" void kernel_launch(void* const* d_in, const int* in_sizes, int n_in,
                              void* d_out, int out_size, void* d_ws,
                              size_t ws_size, hipStream_t stream) {
  (void)in_sizes; (void)n_in; (void)out_size; (void)ws_size;
  const float* query = (const float*)d_in[0];
  const float* refp  = (const float*)d_in[1];
  const float* inpf  = (const float*)d_in[2];
  const float* Woff  = (const float*)d_in[5];
  const float* boff  = (const float*)d_in[6];
  const float* Wattn = (const float*)d_in[7];
  const float* battn = (const float*)d_in[8];
  const float* Wval  = (const float*)d_in[9];
  const float* bval  = (const float*)d_in[10];
  const float* Wout  = (const float*)d_in[11];
  const float* bout  = (const float*)d_in[12];

  // ws: value16 22.3MB | off16 22.3MB | logit16 11.1MB | WT f16 ~0.45MB
  ushort* value16 = (ushort*)d_ws;
  ushort* off16   = value16 + (size_t)MROWS * 256;
  ushort* logit16 = off16 + (size_t)MROWS * 256;
  ushort* WTv     = logit16 + (size_t)MROWS * 128;
  ushort* WTol    = WTv + 65536;   // [384][256]
  ushort* WTu     = WTol + 98304;

  ushort* midb = (ushort*)d_out;   // mid f16 in-place per row (stride 512)

  wt_cvt_all<<<896, 256, 0, stream>>>(Wval, Woff, Wattn, Wout, WTv, WTol, WTu);

  gemm_front<<<680, 512, 0, stream>>>(inpf, WTv, bval, value16, query, WTol,
                                      boff, battn, off16, logit16);

  msda_sample<<<MROWS / 8, 256, 0, stream>>>(off16, logit16, refp, value16,
                                             midb);

  gemm_out<<<MROWS / 128, 512, 0, stream>>>(midb, WTu, bout, (float*)d_out);
}

// Round 6
// 131.503 us; speedup vs baseline: 1.0783x; 1.0694x over previous
//
#include <hip/hip_runtime.h>
#include <hip/hip_fp16.h>
#include <type_traits>

#define LQ 21760
#define MROWS 43520
#define LEN 21760

typedef __attribute__((ext_vector_type(8))) _Float16 half8;
typedef __attribute__((ext_vector_type(4))) float f32x4;

__device__ __forceinline__ uint pkh(float a, float b) {
  auto v = __builtin_amdgcn_cvt_pkrtz(a, b);
  return __builtin_bit_cast(uint, v);
}
__device__ __forceinline__ ushort h16(float x) {
  return __half_as_ushort(__float2half(x));
}
__device__ __forceinline__ float hlo(uint u) {
  return __half2float(__ushort_as_half((ushort)(u & 0xffffu)));
}
__device__ __forceinline__ float hhi(uint u) {
  return __half2float(__ushort_as_half((ushort)(u >> 16)));
}

// ushort index of the 16B slot for (row, k8) with XOR swizzle (<=2-way banks)
__device__ __forceinline__ int swz8(int row, int k8) {
  return row * 32 + ((k8 ^ (row & 3) ^ ((row >> 2) & 3)) << 3);
}

// ---- f16 MFMA GEMM body, double-buffered LDS, 1 barrier per K-step --------
// C[128, BN] = A[128, K=256] @ WT^T + bias. 512 thr = 8 waves (2M x 4N).
template <int BN, bool SPLIT, typename AT, typename OT>
__device__ __forceinline__ void gemm_body(
    const AT* __restrict__ A, int lda, const ushort* __restrict__ WT,
    const float* __restrict__ bias, const float* __restrict__ bias2,
    OT* __restrict__ Cout, int ldc, ushort* __restrict__ C2, int mblk,
    ushort* Asb, ushort* Bsb) {
  constexpr int WN = BN / 4;
  constexpr int NI = WN / 16;
  constexpr int BSTEP = (BN * 4) / 512;
  const int tid = threadIdx.x;
  const int m0 = mblk * 128;
  const int w = tid >> 6, wm = w >> 2, wn = w & 3;
  const int l = tid & 63, lr = l & 15, lk = l >> 4;
  const int arow = tid >> 2, ak8 = tid & 3;

  f32x4 acc[4][NI];
#pragma unroll
  for (int mi = 0; mi < 4; ++mi)
#pragma unroll
    for (int ni = 0; ni < NI; ++ni) acc[mi][ni] = {0.f, 0.f, 0.f, 0.f};

  float4 aF0, aF1;
  uint4 aR;
  uint4 bR[BSTEP];

  auto loadA = [&](int k0) {
    const AT* src = A + (size_t)(m0 + arow) * lda + k0 + ak8 * 8;
    if constexpr (std::is_same_v<AT, float>) {
      aF0 = *(const float4*)src;
      aF1 = *(const float4*)(src + 4);
    } else {
      aR = *(const uint4*)src;
    }
  };
  auto loadB = [&](int k0) {
#pragma unroll
    for (int i = 0; i < BSTEP; ++i) {
      int s = tid + i * 512;
      bR[i] = *(const uint4*)(WT + (size_t)(s >> 2) * 256 + k0 + (s & 3) * 8);
    }
  };
  auto writeLDS = [&](int cur) {
    ushort* Ab = Asb + cur * (128 * 32);
    ushort* Bb = Bsb + cur * (BN * 32);
    uint4 pk;
    if constexpr (std::is_same_v<AT, float>)
      pk = make_uint4(pkh(aF0.x, aF0.y), pkh(aF0.z, aF0.w),
                      pkh(aF1.x, aF1.y), pkh(aF1.z, aF1.w));
    else
      pk = aR;
    *(uint4*)&Ab[swz8(arow, ak8)] = pk;
#pragma unroll
    for (int i = 0; i < BSTEP; ++i) {
      int s = tid + i * 512;
      *(uint4*)&Bb[swz8(s >> 2, s & 3)] = bR[i];
    }
  };

  loadA(0);
  loadB(0);
#pragma unroll
  for (int ks = 0; ks < 8; ++ks) {
    const int cur = ks & 1;
    writeLDS(cur);
    __syncthreads();
    if (ks < 7) {  // prefetch AFTER barrier: overlaps ds_read + MFMA below
      loadA((ks + 1) * 32);
      loadB((ks + 1) * 32);
    }
    const ushort* Ab = Asb + cur * (128 * 32);
    const ushort* Bb = Bsb + cur * (BN * 32);
    half8 af[4], bfr[NI];
#pragma unroll
    for (int mi = 0; mi < 4; ++mi)
      af[mi] = *(const half8*)&Ab[swz8(wm * 64 + mi * 16 + lr, lk)];
#pragma unroll
    for (int ni = 0; ni < NI; ++ni)
      bfr[ni] = *(const half8*)&Bb[swz8(wn * WN + ni * 16 + lr, lk)];
#pragma unroll
    for (int mi = 0; mi < 4; ++mi)
#pragma unroll
      for (int ni = 0; ni < NI; ++ni)
        acc[mi][ni] = __builtin_amdgcn_mfma_f32_16x16x32_f16(
            af[mi], bfr[ni], acc[mi][ni], 0, 0, 0);
  }
#pragma unroll
  for (int mi = 0; mi < 4; ++mi) {
#pragma unroll
    for (int ni = 0; ni < NI; ++ni) {
      int col = wn * WN + ni * 16 + lr;
      float bs;
      if constexpr (SPLIT)
        bs = (col < 256) ? bias[col] : bias2[col - 256];
      else
        bs = bias[col];
      int row = m0 + wm * 64 + mi * 16 + lk * 4;
#pragma unroll
      for (int r = 0; r < 4; ++r) {
        float v = acc[mi][ni][r] + bs;
        if constexpr (SPLIT) {
          if (col < 256)
            ((ushort*)Cout)[(size_t)(row + r) * 256 + col] = h16(v);
          else
            C2[(size_t)(row + r) * 128 + col - 256] = h16(v);
        } else if constexpr (std::is_same_v<OT, ushort>) {
          Cout[(size_t)(row + r) * ldc + col] = h16(v);
        } else {
          Cout[(size_t)(row + r) * ldc + col] = v;
        }
      }
    }
  }
}

// ---- front: blocks 0..339 -> value GEMM, 340..679 -> offsets+logits GEMM ---
__global__ __launch_bounds__(512) void gemm_front(
    const float* __restrict__ inpf, const ushort* __restrict__ WTv,
    const float* __restrict__ bval, ushort* __restrict__ value16,
    const float* __restrict__ query, const ushort* __restrict__ WTol,
    const float* __restrict__ boff, const float* __restrict__ battn,
    ushort* __restrict__ off16, ushort* __restrict__ logit16) {
  __shared__ ushort Asb[2 * 128 * 32];
  __shared__ ushort Bsb[2 * 384 * 32];
  int bid = blockIdx.x;
  if (bid < 340) {
    gemm_body<256, false, float, ushort>(inpf, 256, WTv, bval, nullptr,
                                         value16, 256, nullptr, bid, Asb, Bsb);
  } else {
    gemm_body<384, true, float, ushort>(query, 256, WTol, boff, battn, off16,
                                        256, logit16, bid - 340, Asb, Bsb);
  }
}

__global__ __launch_bounds__(512) void gemm_out(
    const ushort* __restrict__ midb, const ushort* __restrict__ WTu,
    const float* __restrict__ bout, float* __restrict__ outp) {
  __shared__ ushort Asb[2 * 128 * 32];
  __shared__ ushort Bsb[2 * 256 * 32];
  gemm_body<256, false, ushort, float>(midb, 512, WTu, bout, nullptr, outp,
                                       256, nullptr, blockIdx.x, Asb, Bsb);
}

// -------- prep: all weight transposes (f32 [K][N] -> f16 [N][256]) ----------
__global__ __launch_bounds__(256) void wt_cvt_all(
    const float* __restrict__ Wval, const float* __restrict__ Woff,
    const float* __restrict__ Wattn, const float* __restrict__ Wout,
    ushort* __restrict__ WTv, ushort* __restrict__ WTol,
    ushort* __restrict__ WTu) {
  int i = blockIdx.x * 256 + threadIdx.x;  // < 229376
  if (i < 65536) {
    int n = i >> 8, k = i & 255;
    WTv[i] = h16(Wval[(size_t)k * 256 + n]);
  } else if (i < 163840) {
    int j = i - 65536;
    int n = j >> 8, k = j & 255;
    float s = (n < 256) ? Woff[(size_t)k * 256 + n] : Wattn[(size_t)k * 128 + n - 256];
    WTol[j] = h16(s);
  } else {
    int j = i - 163840;
    int n = j >> 8, k = j & 255;
    WTu[j] = h16(Wout[(size_t)k * 256 + n]);
  }
}

// ------------- sampler: XCD-pinned (batch, head-pair) groups ----------------
// block = 256 thr; grp = blockIdx&7 -> (batch, head-pair); 32 queries/block.
// FINAL CONFIG (measured best, 70.9 us). Negative results, do NOT revisit:
//  - explicit SW-pipelined gathers: scheduler clamps VGPR + serializes
//    (r1: 40 VGPR +13us, r2: 44 VGPR +11us)
//  - LDS shrink to 21.5KB for occupancy 58%: slower (r5, +7us) -> gather is
//    L2-throughput-bound (~20 TB/s random-64B, ~58% of streaming ceiling),
//    not latency-bound
//  - level-major gather order for L1 reuse: slower (r4, +7us)
//  - pk_fma instead of fma_mix: VALU 58->48% but time unchanged (r3) ->
//    not VALU-bound (kept fma_mix: marginally best measured)
__global__ __launch_bounds__(256) void msda_sample(
    const ushort* __restrict__ off16,   // [M][256] f16
    const ushort* __restrict__ logit16, // [M][128] f16
    const float* __restrict__ refpts,   // [M][4][2]
    const ushort* __restrict__ value,   // [B][LEN][256] f16
    ushort* __restrict__ midb) {        // f16, row r at midb + r*512
  __shared__ float prs[64][16];   // 4 KB
  __shared__ float refs[32][4][2];
  __shared__ int tix[1024][4];    // 16 KB
  __shared__ uint twp[1024][2];   // 8 KB

  const int bid = blockIdx.x;
  const int grp = bid & 7;        // -> XCD (round-robin dispatch assumption)
  const int sub = bid >> 3;       // 0..679
  const int b = grp >> 2;
  const int hp = grp & 3;         // head pair: heads 2hp, 2hp+1
  const int q0 = sub * 32;
  const int tid = threadIdx.x;
  const size_t fqB = (size_t)b * LQ + q0;

  // ---- A0: refs (32q x 8 vals, 1/thread) + softmax for 64 (q, h') pairs ----
  {
    int q = tid >> 3, r = tid & 7;
    refs[q][r >> 1][r & 1] = refpts[(fqB + q) * 8 + r];
  }
  if (tid < 64) {
    int q = tid >> 1, hh = tid & 1;
    int h = hp * 2 + hh;
    const uint4* lp = (const uint4*)(logit16 + (fqB + q) * 128 + h * 16);
    uint4 p0 = lp[0], p1 = lp[1];
    float v[16] = {hlo(p0.x), hhi(p0.x), hlo(p0.y), hhi(p0.y),
                   hlo(p0.z), hhi(p0.z), hlo(p0.w), hhi(p0.w),
                   hlo(p1.x), hhi(p1.x), hlo(p1.y), hhi(p1.y),
                   hlo(p1.z), hhi(p1.z), hlo(p1.w), hhi(p1.w)};
    float m = v[0];
#pragma unroll
    for (int i = 1; i < 16; ++i) m = fmaxf(m, v[i]);
    float s = 0.f;
#pragma unroll
    for (int i = 0; i < 16; ++i) { v[i] = __expf(v[i] - m); s += v[i]; }
    float inv = 1.0f / s;
#pragma unroll
    for (int i = 0; i < 16; ++i) prs[tid][i] = v[i] * inv;
  }
  __syncthreads();

  // ---- A2: 1024 tasks (q 0..31, h' 0..1, lp 0..15), 4 per thread ----
#pragma unroll
  for (int i = 0; i < 4; ++i) {
    int t = tid + i * 256;
    int q = t >> 5;
    int hh = (t >> 4) & 1;
    int lp_ = t & 15;
    int lvl = lp_ >> 2;
    int h = hp * 2 + hh;
    uint op = ((const uint*)off16)[(fqB + q) * 128 + h * 16 + lp_];
    float ox = hlo(op), oy = hhi(op);
    float aw = prs[q * 2 + hh][lp_];
    float rx = refs[q][lvl][0], ry = refs[q][lvl][1];
    int Wl = 128 >> lvl;
    int st = (lvl == 0) ? 0 : ((lvl == 1) ? 16384 : ((lvl == 2) ? 20480 : 21504));
    float fW = (float)Wl;
    float invW = 1.0f / fW;
    float x = (rx + ox * invW) * fW - 0.5f;
    float y = (ry + oy * invW) * fW - 0.5f;
    float x0f = floorf(x), y0f = floorf(y);
    float wx1 = x - x0f, wy1 = y - y0f;
    float wx0 = 1.f - wx1, wy0 = 1.f - wy1;
    int x0 = (int)x0f, y0 = (int)y0f;
    int x1 = x0 + 1, y1 = y0 + 1;
    bool vx0 = (x0 >= 0) & (x0 < Wl), vx1 = (x1 >= 0) & (x1 < Wl);
    bool vy0 = (y0 >= 0) & (y0 < Wl), vy1 = (y1 >= 0) & (y1 < Wl);
    int xc0 = min(max(x0, 0), Wl - 1), xc1 = min(max(x1, 0), Wl - 1);
    int yc0 = min(max(y0, 0), Wl - 1), yc1 = min(max(y1, 0), Wl - 1);
    int base = st * 256 + h * 32;
    int g16 = t >> 4;
    int slot = (t & ~15) | ((t + g16) & 15);
    float w00 = (vx0 && vy0) ? wx0 * wy0 * aw : 0.f;
    float w10 = (vx1 && vy0) ? wx1 * wy0 * aw : 0.f;
    float w01 = (vx0 && vy1) ? wx0 * wy1 * aw : 0.f;
    float w11 = (vx1 && vy1) ? wx1 * wy1 * aw : 0.f;
    tix[slot][0] = base + (yc0 * Wl + xc0) * 256;
    tix[slot][1] = base + (yc0 * Wl + xc1) * 256;
    tix[slot][2] = base + (yc1 * Wl + xc0) * 256;
    tix[slot][3] = base + (yc1 * Wl + xc1) * 256;
    twp[slot][0] = pkh(w00, w10);
    twp[slot][1] = pkh(w01, w11);
  }
  __syncthreads();

  // ---- B: gather. 4 lanes per (q,h'); lane owns 8 dims (16B f16 loads) ----
  const int g = tid >> 2;
  const int dl = tid & 3;
  const ushort* vb = value + (size_t)b * LEN * 256 + dl * 8;
  float a0 = 0.f, a1 = 0.f, a2 = 0.f, a3 = 0.f;
  float a4 = 0.f, a5 = 0.f, a6 = 0.f, a7 = 0.f;
  const int tb = g * 16;

#define FMAMIX(ACC, WP, U, OPSEL) \
  asm("v_fma_mix_f32 %0, %1, %2, %0 " OPSEL : "+v"(ACC) : "v"(WP), "v"(U))
#define CORNER(U, WPW, WS)                                              \
  FMAMIX(a0, WPW, (U).x, "op_sel:[" WS ",0,0] op_sel_hi:[1,1,0]");      \
  FMAMIX(a1, WPW, (U).x, "op_sel:[" WS ",1,0] op_sel_hi:[1,1,0]");      \
  FMAMIX(a2, WPW, (U).y, "op_sel:[" WS ",0,0] op_sel_hi:[1,1,0]");      \
  FMAMIX(a3, WPW, (U).y, "op_sel:[" WS ",1,0] op_sel_hi:[1,1,0]");      \
  FMAMIX(a4, WPW, (U).z, "op_sel:[" WS ",0,0] op_sel_hi:[1,1,0]");      \
  FMAMIX(a5, WPW, (U).z, "op_sel:[" WS ",1,0] op_sel_hi:[1,1,0]");      \
  FMAMIX(a6, WPW, (U).w, "op_sel:[" WS ",0,0] op_sel_hi:[1,1,0]");      \
  FMAMIX(a7, WPW, (U).w, "op_sel:[" WS ",1,0] op_sel_hi:[1,1,0]")

#pragma unroll 4
  for (int t = 0; t < 16; ++t) {
    int slot = tb + ((t + g) & 15);
    int4 ix = *(const int4*)&tix[slot][0];
    uint2 wp = *(const uint2*)&twp[slot][0];
    uint4 u0 = *(const uint4*)(vb + ix.x);
    uint4 u1 = *(const uint4*)(vb + ix.y);
    uint4 u2 = *(const uint4*)(vb + ix.z);
    uint4 u3 = *(const uint4*)(vb + ix.w);
    CORNER(u0, wp.x, "0");
    CORNER(u1, wp.x, "1");
    CORNER(u2, wp.y, "0");
    CORNER(u3, wp.y, "1");
  }
#undef CORNER
#undef FMAMIX

  const int q = g >> 1, h = hp * 2 + (g & 1);
  ushort* mp = midb + (fqB + q) * 512 + h * 32 + dl * 8;
  *(uint4*)mp = make_uint4(pkh(a0, a1), pkh(a2, a3), pkh(a4, a5), pkh(a6, a7));
}

extern "C" void kernel_launch(void* const* d_in, const int* in_sizes, int n_in,
                              void* d_out, int out_size, void* d_ws,
                              size_t ws_size, hipStream_t stream) {
  (void)in_sizes; (void)n_in; (void)out_size; (void)ws_size;
  const float* query = (const float*)d_in[0];
  const float* refp  = (const float*)d_in[1];
  const float* inpf  = (const float*)d_in[2];
  const float* Woff  = (const float*)d_in[5];
  const float* boff  = (const float*)d_in[6];
  const float* Wattn = (const float*)d_in[7];
  const float* battn = (const float*)d_in[8];
  const float* Wval  = (const float*)d_in[9];
  const float* bval  = (const float*)d_in[10];
  const float* Wout  = (const float*)d_in[11];
  const float* bout  = (const float*)d_in[12];

  // ws: value16 22.3MB | off16 22.3MB | logit16 11.1MB | WT f16 ~0.45MB
  ushort* value16 = (ushort*)d_ws;
  ushort* off16   = value16 + (size_t)MROWS * 256;
  ushort* logit16 = off16 + (size_t)MROWS * 256;
  ushort* WTv     = logit16 + (size_t)MROWS * 128;
  ushort* WTol    = WTv + 65536;   // [384][256]
  ushort* WTu     = WTol + 98304;

  ushort* midb = (ushort*)d_out;   // mid f16 in-place per row (stride 512)

  wt_cvt_all<<<896, 256, 0, stream>>>(Wval, Woff, Wattn, Wout, WTv, WTol, WTu);

  gemm_front<<<680, 512, 0, stream>>>(inpf, WTv, bval, value16, query, WTol,
                                      boff, battn, off16, logit16);

  msda_sample<<<MROWS / 8, 256, 0, stream>>>(off16, logit16, refp, value16,
                                             midb);

  gemm_out<<<MROWS / 128, 512, 0, stream>>>(midb, WTu, bout, (float*)d_out);
}

// Round 7
// 128.009 us; speedup vs baseline: 1.1077x; 1.0273x over previous
//
#include <hip/hip_runtime.h>
#include <hip/hip_fp16.h>
#include <type_traits>

#define LQ 21760
#define MROWS 43520
#define LEN 21760

typedef __attribute__((ext_vector_type(8))) _Float16 half8;
typedef __attribute__((ext_vector_type(4))) float f32x4;

__device__ __forceinline__ uint pkh(float a, float b) {
  auto v = __builtin_amdgcn_cvt_pkrtz(a, b);
  return __builtin_bit_cast(uint, v);
}
__device__ __forceinline__ ushort h16(float x) {
  return __half_as_ushort(__float2half(x));
}
__device__ __forceinline__ float hlo(uint u) {
  return __half2float(__ushort_as_half((ushort)(u & 0xffffu)));
}
__device__ __forceinline__ float hhi(uint u) {
  return __half2float(__ushort_as_half((ushort)(u >> 16)));
}

// ushort index of the 16B slot for (row, k8) with XOR swizzle (<=2-way banks)
__device__ __forceinline__ int swz8(int row, int k8) {
  return row * 32 + ((k8 ^ (row & 3) ^ ((row >> 2) & 3)) << 3);
}

// ---- f16 MFMA GEMM body, double-buffered LDS, 1 barrier per K-step --------
// C[128, BN] = A[128, K=256] @ WT^T + bias. 512 thr = 8 waves (2M x 4N).
// VT: write C in head-major layout [B][8][LQ][32] (for the sampler's
// contiguous x-pair gathers). Requires 128-row blocks not to straddle the
// batch boundary (21760 % 128 == 0: holds).
template <int BN, bool SPLIT, bool VT, typename AT, typename OT>
__device__ __forceinline__ void gemm_body(
    const AT* __restrict__ A, int lda, const ushort* __restrict__ WT,
    const float* __restrict__ bias, const float* __restrict__ bias2,
    OT* __restrict__ Cout, int ldc, ushort* __restrict__ C2, int mblk,
    ushort* Asb, ushort* Bsb) {
  constexpr int WN = BN / 4;
  constexpr int NI = WN / 16;
  constexpr int BSTEP = (BN * 4) / 512;
  const int tid = threadIdx.x;
  const int m0 = mblk * 128;
  const int w = tid >> 6, wm = w >> 2, wn = w & 3;
  const int l = tid & 63, lr = l & 15, lk = l >> 4;
  const int arow = tid >> 2, ak8 = tid & 3;

  f32x4 acc[4][NI];
#pragma unroll
  for (int mi = 0; mi < 4; ++mi)
#pragma unroll
    for (int ni = 0; ni < NI; ++ni) acc[mi][ni] = {0.f, 0.f, 0.f, 0.f};

  float4 aF0, aF1;
  uint4 aR;
  uint4 bR[BSTEP];

  auto loadA = [&](int k0) {
    const AT* src = A + (size_t)(m0 + arow) * lda + k0 + ak8 * 8;
    if constexpr (std::is_same_v<AT, float>) {
      aF0 = *(const float4*)src;
      aF1 = *(const float4*)(src + 4);
    } else {
      aR = *(const uint4*)src;
    }
  };
  auto loadB = [&](int k0) {
#pragma unroll
    for (int i = 0; i < BSTEP; ++i) {
      int s = tid + i * 512;
      bR[i] = *(const uint4*)(WT + (size_t)(s >> 2) * 256 + k0 + (s & 3) * 8);
    }
  };
  auto writeLDS = [&](int cur) {
    ushort* Ab = Asb + cur * (128 * 32);
    ushort* Bb = Bsb + cur * (BN * 32);
    uint4 pk;
    if constexpr (std::is_same_v<AT, float>)
      pk = make_uint4(pkh(aF0.x, aF0.y), pkh(aF0.z, aF0.w),
                      pkh(aF1.x, aF1.y), pkh(aF1.z, aF1.w));
    else
      pk = aR;
    *(uint4*)&Ab[swz8(arow, ak8)] = pk;
#pragma unroll
    for (int i = 0; i < BSTEP; ++i) {
      int s = tid + i * 512;
      *(uint4*)&Bb[swz8(s >> 2, s & 3)] = bR[i];
    }
  };

  loadA(0);
  loadB(0);
#pragma unroll
  for (int ks = 0; ks < 8; ++ks) {
    const int cur = ks & 1;
    writeLDS(cur);
    __syncthreads();
    if (ks < 7) {  // prefetch AFTER barrier: overlaps ds_read + MFMA below
      loadA((ks + 1) * 32);
      loadB((ks + 1) * 32);
    }
    const ushort* Ab = Asb + cur * (128 * 32);
    const ushort* Bb = Bsb + cur * (BN * 32);
    half8 af[4], bfr[NI];
#pragma unroll
    for (int mi = 0; mi < 4; ++mi)
      af[mi] = *(const half8*)&Ab[swz8(wm * 64 + mi * 16 + lr, lk)];
#pragma unroll
    for (int ni = 0; ni < NI; ++ni)
      bfr[ni] = *(const half8*)&Bb[swz8(wn * WN + ni * 16 + lr, lk)];
#pragma unroll
    for (int mi = 0; mi < 4; ++mi)
#pragma unroll
      for (int ni = 0; ni < NI; ++ni)
        acc[mi][ni] = __builtin_amdgcn_mfma_f32_16x16x32_f16(
            af[mi], bfr[ni], acc[mi][ni], 0, 0, 0);
  }
#pragma unroll
  for (int mi = 0; mi < 4; ++mi) {
#pragma unroll
    for (int ni = 0; ni < NI; ++ni) {
      int col = wn * WN + ni * 16 + lr;
      float bs;
      if constexpr (SPLIT)
        bs = (col < 256) ? bias[col] : bias2[col - 256];
      else
        bs = bias[col];
      int row = m0 + wm * 64 + mi * 16 + lk * 4;
#pragma unroll
      for (int r = 0; r < 4; ++r) {
        float v = acc[mi][ni][r] + bs;
        if constexpr (SPLIT) {
          if (col < 256)
            ((ushort*)Cout)[(size_t)(row + r) * 256 + col] = h16(v);
          else
            C2[(size_t)(row + r) * 128 + col - 256] = h16(v);
        } else if constexpr (VT) {
          int rr = row + r;
          int bb = (rr >= LQ) ? 1 : 0;
          int pos = rr - bb * LQ;
          size_t idx =
              ((size_t)(bb * 8 + (col >> 5)) * LQ + pos) * 32 + (col & 31);
          ((ushort*)Cout)[idx] = h16(v);
        } else if constexpr (std::is_same_v<OT, ushort>) {
          Cout[(size_t)(row + r) * ldc + col] = h16(v);
        } else {
          Cout[(size_t)(row + r) * ldc + col] = v;
        }
      }
    }
  }
}

// ---- front: blocks 0..339 -> value GEMM, 340..679 -> offsets+logits GEMM ---
__global__ __launch_bounds__(512) void gemm_front(
    const float* __restrict__ inpf, const ushort* __restrict__ WTv,
    const float* __restrict__ bval, ushort* __restrict__ value16,
    const float* __restrict__ query, const ushort* __restrict__ WTol,
    const float* __restrict__ boff, const float* __restrict__ battn,
    ushort* __restrict__ off16, ushort* __restrict__ logit16) {
  __shared__ ushort Asb[2 * 128 * 32];
  __shared__ ushort Bsb[2 * 384 * 32];
  int bid = blockIdx.x;
  if (bid < 340) {
    gemm_body<256, false, true, float, ushort>(
        inpf, 256, WTv, bval, nullptr, value16, 256, nullptr, bid, Asb, Bsb);
  } else {
    gemm_body<384, true, false, float, ushort>(query, 256, WTol, boff, battn,
                                               off16, 256, logit16, bid - 340,
                                               Asb, Bsb);
  }
}

__global__ __launch_bounds__(512) void gemm_out(
    const ushort* __restrict__ midb, const ushort* __restrict__ WTu,
    const float* __restrict__ bout, float* __restrict__ outp) {
  __shared__ ushort Asb[2 * 128 * 32];
  __shared__ ushort Bsb[2 * 256 * 32];
  gemm_body<256, false, false, ushort, float>(midb, 512, WTu, bout, nullptr,
                                              outp, 256, nullptr, blockIdx.x,
                                              Asb, Bsb);
}

// -------- prep: all weight transposes (f32 [K][N] -> f16 [N][256]) ----------
__global__ __launch_bounds__(256) void wt_cvt_all(
    const float* __restrict__ Wval, const float* __restrict__ Woff,
    const float* __restrict__ Wattn, const float* __restrict__ Wout,
    ushort* __restrict__ WTv, ushort* __restrict__ WTol,
    ushort* __restrict__ WTu) {
  int i = blockIdx.x * 256 + threadIdx.x;  // < 229376
  if (i < 65536) {
    int n = i >> 8, k = i & 255;
    WTv[i] = h16(Wval[(size_t)k * 256 + n]);
  } else if (i < 163840) {
    int j = i - 65536;
    int n = j >> 8, k = j & 255;
    float s = (n < 256) ? Woff[(size_t)k * 256 + n] : Wattn[(size_t)k * 128 + n - 256];
    WTol[j] = h16(s);
  } else {
    int j = i - 163840;
    int n = j >> 8, k = j & 255;
    WTu[j] = h16(Wout[(size_t)k * 256 + n]);
  }
}

// ------------- sampler: XCD-pinned (batch, head-pair) groups ----------------
// block = 256 thr; grp = blockIdx&7 -> (batch, head-pair); 32 queries/block.
// value is HEAD-MAJOR [B][8][LQ][32]: the x-corner pair of a bilinear tap is
// 128 B contiguous. Gather uses 8 lanes per (q,h') covering the pair with one
// wave-load -> 8 x 128B contiguous requests/instr instead of 16 x 64B
// scattered (2x fewer TA/L2 requests; bytes unchanged). x-pair partial sums
// combined by shfl_xor(4). Clamp edge handled by weight-swap at record build
// (x0<0: left slot carries w10); over-reads past row/level end are
// in-workspace, finite, x0-weighted.
// LDS padded to exactly 29,696 B: shrinking it raises the occupancy target
// and clamps VGPR (round-5: slower). No launch_bounds min-waves for same
// reason. Simple loop shape: explicit SW pipelines get re-serialized
// (rounds 1-2).
__global__ __launch_bounds__(256) void msda_sample(
    const ushort* __restrict__ off16,   // [M][256] f16
    const ushort* __restrict__ logit16, // [M][128] f16
    const float* __restrict__ refpts,   // [M][4][2]
    const ushort* __restrict__ value,   // [B][8][LQ][32] f16 (head-major)
    ushort* __restrict__ midb) {        // f16, row r at midb + r*512
  __shared__ float prs[64][16];   // 4 KB
  __shared__ float refs[32][4][2];
  __shared__ int tix[1024][4];    // 16 KB ([2],[3] unused: occupancy pad)
  __shared__ uint twp[1024][2];   // 8 KB

  const int bid = blockIdx.x;
  const int grp = bid & 7;        // -> XCD (round-robin dispatch assumption)
  const int sub = bid >> 3;       // 0..679
  const int b = grp >> 2;
  const int hp = grp & 3;         // head pair: heads 2hp, 2hp+1
  const int q0 = sub * 32;
  const int tid = threadIdx.x;
  const size_t fqB = (size_t)b * LQ + q0;

  // ---- A0: refs (32q x 8 vals, 1/thread) + softmax for 64 (q, h') pairs ----
  {
    int q = tid >> 3, r = tid & 7;
    refs[q][r >> 1][r & 1] = refpts[(fqB + q) * 8 + r];
  }
  if (tid < 64) {
    int q = tid >> 1, hh = tid & 1;
    int h = hp * 2 + hh;
    const uint4* lp = (const uint4*)(logit16 + (fqB + q) * 128 + h * 16);
    uint4 p0 = lp[0], p1 = lp[1];
    float v[16] = {hlo(p0.x), hhi(p0.x), hlo(p0.y), hhi(p0.y),
                   hlo(p0.z), hhi(p0.z), hlo(p0.w), hhi(p0.w),
                   hlo(p1.x), hhi(p1.x), hlo(p1.y), hhi(p1.y),
                   hlo(p1.z), hhi(p1.z), hlo(p1.w), hhi(p1.w)};
    float m = v[0];
#pragma unroll
    for (int i = 1; i < 16; ++i) m = fmaxf(m, v[i]);
    float s = 0.f;
#pragma unroll
    for (int i = 0; i < 16; ++i) { v[i] = __expf(v[i] - m); s += v[i]; }
    float inv = 1.0f / s;
#pragma unroll
    for (int i = 0; i < 16; ++i) prs[tid][i] = v[i] * inv;
  }
  __syncthreads();

  // ---- A2: 1024 tasks (q 0..31, h' 0..1, lp 0..15), 4 per thread ----
#pragma unroll
  for (int i = 0; i < 4; ++i) {
    int t = tid + i * 256;
    int q = t >> 5;
    int hh = (t >> 4) & 1;
    int lp_ = t & 15;
    int lvl = lp_ >> 2;
    int h = hp * 2 + hh;
    uint op = ((const uint*)off16)[(fqB + q) * 128 + h * 16 + lp_];
    float ox = hlo(op), oy = hhi(op);
    float aw = prs[q * 2 + hh][lp_];
    float rx = refs[q][lvl][0], ry = refs[q][lvl][1];
    int Wl = 128 >> lvl;
    int st = (lvl == 0) ? 0 : ((lvl == 1) ? 16384 : ((lvl == 2) ? 20480 : 21504));
    float fW = (float)Wl;
    float invW = 1.0f / fW;
    float x = (rx + ox * invW) * fW - 0.5f;
    float y = (ry + oy * invW) * fW - 0.5f;
    float x0f = floorf(x), y0f = floorf(y);
    float wx1 = x - x0f, wy1 = y - y0f;
    float wx0 = 1.f - wx1, wy0 = 1.f - wy1;
    int x0 = (int)x0f, y0 = (int)y0f;
    int x1 = x0 + 1, y1 = y0 + 1;
    bool vx0 = (x0 >= 0) & (x0 < Wl), vx1 = (x1 >= 0) & (x1 < Wl);
    bool vy0 = (y0 >= 0) & (y0 < Wl), vy1 = (y1 >= 0) & (y1 < Wl);
    int xc0 = min(max(x0, 0), Wl - 1);
    int yc0 = min(max(y0, 0), Wl - 1), yc1 = min(max(y1, 0), Wl - 1);
    float w00 = (vx0 && vy0) ? wx0 * wy0 * aw : 0.f;
    float w10 = (vx1 && vy0) ? wx1 * wy0 * aw : 0.f;
    float w01 = (vx0 && vy1) ? wx0 * wy1 * aw : 0.f;
    float w11 = (vx1 && vy1) ? wx1 * wy1 * aw : 0.f;
    // weight swap: if x0<0, pixel xc0(=0) IS the x1 corner -> lo slot = w10
    bool xs = (x0 < 0);
    float lo0 = xs ? w10 : w00, hi0 = xs ? 0.f : w10;
    float lo1 = xs ? w11 : w01, hi1 = xs ? 0.f : w11;
    // head-major byte offsets: pixel stride 64 B, x-pair contiguous 128 B
    int baseB = (h * LQ + st + yc0 * Wl + xc0) * 64;
    int dyB = (yc1 - yc0) * Wl * 64;
    // stagger keyed by GATHER group (qh>>1 = t>>5) so reads walk distinct rows
    int slot = (t & ~15) | ((lp_ + (t >> 5)) & 15);
    tix[slot][0] = baseB;
    tix[slot][1] = dyB;
    twp[slot][0] = pkh(lo0, hi0);
    twp[slot][1] = pkh(lo1, hi1);
  }
  __syncthreads();

  // ---- B: gather. 8 lanes per (q,h'); lanes<4 own x0 dims, lanes>=4 x1 ----
  const int g8 = tid >> 3;        // 32 groups
  const int dl = tid & 7;
  const uint dlB = (uint)dl * 16u;          // covers the 128B x-pair
  const uint sh = (uint)((tid & 4) << 2);   // 0 (lo weight) / 16 (hi weight)
  const char* vb0c = (const char*)(value + (size_t)b * (LEN * 256));

// packed f16 FMA, weight word pre-shifted so lo half is always the weight;
// op_sel broadcasts weight.lo to both halves.
#define PKC(ACC, U, WP)                                                 \
  asm("v_pk_fma_f16 %0, %1, %2, %0 op_sel:[0,0,0] op_sel_hi:[1,0,1]"    \
      : "+v"(ACC)                                                       \
      : "v"(U), "v"(WP))
// promote f16x2 chunk into two f32 accumulators, then reset chunk
#define PROMO1(ALO, AHI, C)                                             \
  asm("v_fma_mix_f32 %0, 1.0, %1, %0 op_sel:[0,0,0] op_sel_hi:[0,1,0]"  \
      : "+v"(ALO) : "v"(C));                                            \
  asm("v_fma_mix_f32 %0, 1.0, %1, %0 op_sel:[0,1,0] op_sel_hi:[0,1,0]"  \
      : "+v"(AHI) : "v"(C));                                            \
  C = 0u;

#pragma unroll
  for (int half = 0; half < 2; ++half) {
    const int qh = g8 * 2 + half;
    const int tb2 = qh * 16;
    float a0 = 0.f, a1 = 0.f, a2 = 0.f, a3 = 0.f;
    float a4 = 0.f, a5 = 0.f, a6 = 0.f, a7 = 0.f;
    uint c0 = 0u, c1 = 0u, c2 = 0u, c3 = 0u;
#pragma unroll 4
    for (int t = 0; t < 16; ++t) {
      int slot = tb2 + ((t + g8) & 15);
      int2 bx = *(const int2*)&tix[slot][0];
      uint2 wp = *(const uint2*)&twp[slot][0];
      const char* p0 = vb0c + (uint)bx.x + dlB;
      uint4 u0 = *(const uint4*)p0;
      uint4 u1 = *(const uint4*)(p0 + (uint)bx.y);
      uint wp0 = wp.x >> sh;
      uint wp1 = wp.y >> sh;
      PKC(c0, u0.x, wp0); PKC(c1, u0.y, wp0);
      PKC(c2, u0.z, wp0); PKC(c3, u0.w, wp0);
      PKC(c0, u1.x, wp1); PKC(c1, u1.y, wp1);
      PKC(c2, u1.z, wp1); PKC(c3, u1.w, wp1);
      if ((t & 3) == 3) {  // promote every 4 tasks (8 f16 contributions)
        PROMO1(a0, a1, c0);
        PROMO1(a2, a3, c1);
        PROMO1(a4, a5, c2);
        PROMO1(a6, a7, c3);
      }
    }
    // combine x0/x1 partials across the 8-lane group
    a0 += __shfl_xor(a0, 4); a1 += __shfl_xor(a1, 4);
    a2 += __shfl_xor(a2, 4); a3 += __shfl_xor(a3, 4);
    a4 += __shfl_xor(a4, 4); a5 += __shfl_xor(a5, 4);
    a6 += __shfl_xor(a6, 4); a7 += __shfl_xor(a7, 4);
    if (dl < 4) {
      const int q = qh >> 1, h = hp * 2 + (qh & 1);
      ushort* mp = midb + (fqB + q) * 512 + h * 32 + dl * 8;
      *(uint4*)mp =
          make_uint4(pkh(a0, a1), pkh(a2, a3), pkh(a4, a5), pkh(a6, a7));
    }
  }
#undef PROMO1
#undef PKC
}

extern "C" void kernel_launch(void* const* d_in, const int* in_sizes, int n_in,
                              void* d_out, int out_size, void* d_ws,
                              size_t ws_size, hipStream_t stream) {
  (void)in_sizes; (void)n_in; (void)out_size; (void)ws_size;
  const float* query = (const float*)d_in[0];
  const float* refp  = (const float*)d_in[1];
  const float* inpf  = (const float*)d_in[2];
  const float* Woff  = (const float*)d_in[5];
  const float* boff  = (const float*)d_in[6];
  const float* Wattn = (const float*)d_in[7];
  const float* battn = (const float*)d_in[8];
  const float* Wval  = (const float*)d_in[9];
  const float* bval  = (const float*)d_in[10];
  const float* Wout  = (const float*)d_in[11];
  const float* bout  = (const float*)d_in[12];

  // ws: value16 22.3MB | off16 22.3MB | logit16 11.1MB | WT f16 ~0.45MB
  ushort* value16 = (ushort*)d_ws;
  ushort* off16   = value16 + (size_t)MROWS * 256;
  ushort* logit16 = off16 + (size_t)MROWS * 256;
  ushort* WTv     = logit16 + (size_t)MROWS * 128;
  ushort* WTol    = WTv + 65536;   // [384][256]
  ushort* WTu     = WTol + 98304;

  ushort* midb = (ushort*)d_out;   // mid f16 in-place per row (stride 512)

  wt_cvt_all<<<896, 256, 0, stream>>>(Wval, Woff, Wattn, Wout, WTv, WTol, WTu);

  gemm_front<<<680, 512, 0, stream>>>(inpf, WTv, bval, value16, query, WTol,
                                      boff, battn, off16, logit16);

  msda_sample<<<MROWS / 8, 256, 0, stream>>>(off16, logit16, refp, value16,
                                             midb);

  gemm_out<<<MROWS / 128, 512, 0, stream>>>(midb, WTu, bout, (float*)d_out);
}

// Round 8
// 123.093 us; speedup vs baseline: 1.1520x; 1.0399x over previous
//
#include <hip/hip_runtime.h>
#include <hip/hip_fp16.h>
#include <type_traits>

#define LQ 21760
#define MROWS 43520
#define LEN 21760

typedef __attribute__((ext_vector_type(8))) _Float16 half8;
typedef __attribute__((ext_vector_type(4))) float f32x4;

__device__ __forceinline__ uint pkh(float a, float b) {
  auto v = __builtin_amdgcn_cvt_pkrtz(a, b);
  return __builtin_bit_cast(uint, v);
}
__device__ __forceinline__ ushort h16(float x) {
  return __half_as_ushort(__float2half(x));
}
__device__ __forceinline__ float hlo(uint u) {
  return __half2float(__ushort_as_half((ushort)(u & 0xffffu)));
}
__device__ __forceinline__ float hhi(uint u) {
  return __half2float(__ushort_as_half((ushort)(u >> 16)));
}

// ushort index of the 16B slot for (row, k8) with XOR swizzle (<=2-way banks)
__device__ __forceinline__ int swz8(int row, int k8) {
  return row * 32 + ((k8 ^ (row & 3) ^ ((row >> 2) & 3)) << 3);
}

// async 16B global->LDS (direct, no VGPR round trip). LDS dest is
// wave-uniform base + lane*16; swizzle achieved by pre-swizzled SOURCE.
__device__ __forceinline__ void gll16(const void* g, void* l) {
  __builtin_amdgcn_global_load_lds(
      (const __attribute__((address_space(1))) unsigned int*)g,
      (__attribute__((address_space(3))) unsigned int*)l, 16, 0, 0);
}

// ---- f16 MFMA GEMM body, double-buffered LDS, 1 barrier per K-step --------
// C[128, BN] = A[128, K=256] @ WT^T + bias. 512 thr = 8 waves (2M x 4N).
// B staged via global_load_lds (m97 mechanism, m151: +35% vs reg-staging);
// A also gll when AT==ushort (gemm_out). Source k-chunk pre-swizzled with the
// same involution swz8 uses, LDS dest linear (rule: both-sides-or-neither).
// VT: write C in head-major layout [B][8][LQ][32] for the sampler.
template <int BN, bool SPLIT, bool VT, typename AT, typename OT>
__device__ __forceinline__ void gemm_body(
    const AT* __restrict__ A, int lda, const ushort* __restrict__ WT,
    const float* __restrict__ bias, const float* __restrict__ bias2,
    OT* __restrict__ Cout, int ldc, ushort* __restrict__ C2, int mblk,
    ushort* Asb, ushort* Bsb) {
  constexpr int WN = BN / 4;
  constexpr int NI = WN / 16;
  constexpr int BSTEP = (BN * 4) / 512;
  constexpr bool GLA = std::is_same_v<AT, ushort>;  // A via global_load_lds
  const int tid = threadIdx.x;
  const int m0 = mblk * 128;
  const int w = tid >> 6, wm = w >> 2, wn = w & 3;
  const int l = tid & 63, lr = l & 15, lk = l >> 4;
  const int arow = tid >> 2, ak8 = tid & 3;

  f32x4 acc[4][NI];
#pragma unroll
  for (int mi = 0; mi < 4; ++mi)
#pragma unroll
    for (int ni = 0; ni < NI; ++ni) acc[mi][ni] = {0.f, 0.f, 0.f, 0.f};

  float4 aF0, aF1;

  auto loadA = [&](int k0) {  // f32 A path only (needs cvt)
    const AT* src = A + (size_t)(m0 + arow) * lda + k0 + ak8 * 8;
    if constexpr (std::is_same_v<AT, float>) {
      aF0 = *(const float4*)src;
      aF1 = *(const float4*)(src + 4);
    }
  };
  auto writeA = [&](int cur) {  // f32 A path only
    ushort* Ab = Asb + cur * (128 * 32);
    uint4 pk = make_uint4(pkh(aF0.x, aF0.y), pkh(aF0.z, aF0.w),
                          pkh(aF1.x, aF1.y), pkh(aF1.z, aF1.w));
    *(uint4*)&Ab[swz8(arow, ak8)] = pk;
  };
  auto gllB = [&](int k0, int cur) {
    ushort* Bb = Bsb + cur * (BN * 32);
#pragma unroll
    for (int i = 0; i < BSTEP; ++i) {
      int s = tid + i * 512;
      int row = s >> 2;
      int k8e = (s & 3) ^ (row & 3) ^ ((row >> 2) & 3);  // pre-swizzled src
      gll16(WT + (size_t)row * 256 + k0 + k8e * 8,
            Bb + (size_t)(i * 512 + (tid & ~63)) * 8);
    }
  };
  auto gllA = [&](int k0, int cur) {  // u16 A path (gemm_out)
    ushort* Ab = Asb + cur * (128 * 32);
    int row = tid >> 2;
    int k8e = (tid & 3) ^ (row & 3) ^ ((row >> 2) & 3);
    gll16((const ushort*)A + (size_t)(m0 + row) * lda + k0 + k8e * 8,
          Ab + (size_t)(tid & ~63) * 8);
  };

  if constexpr (!GLA) loadA(0);
  if constexpr (GLA) gllA(0, 0);
  gllB(0, 0);
#pragma unroll
  for (int ks = 0; ks < 8; ++ks) {
    const int cur = ks & 1;
    if constexpr (!GLA) writeA(cur);
    __syncthreads();  // compiler drains vmcnt(0) here: buf[cur] gll complete
    if (ks < 7) {     // prefetch next buffer: stays in flight during MFMA
      if constexpr (GLA) gllA((ks + 1) * 32, cur ^ 1);
      gllB((ks + 1) * 32, cur ^ 1);
      if constexpr (!GLA) loadA((ks + 1) * 32);
    }
    const ushort* Ab = Asb + cur * (128 * 32);
    const ushort* Bb = Bsb + cur * (BN * 32);
    half8 af[4], bfr[NI];
#pragma unroll
    for (int mi = 0; mi < 4; ++mi)
      af[mi] = *(const half8*)&Ab[swz8(wm * 64 + mi * 16 + lr, lk)];
#pragma unroll
    for (int ni = 0; ni < NI; ++ni)
      bfr[ni] = *(const half8*)&Bb[swz8(wn * WN + ni * 16 + lr, lk)];
#pragma unroll
    for (int mi = 0; mi < 4; ++mi)
#pragma unroll
      for (int ni = 0; ni < NI; ++ni)
        acc[mi][ni] = __builtin_amdgcn_mfma_f32_16x16x32_f16(
            af[mi], bfr[ni], acc[mi][ni], 0, 0, 0);
  }
#pragma unroll
  for (int mi = 0; mi < 4; ++mi) {
#pragma unroll
    for (int ni = 0; ni < NI; ++ni) {
      int col = wn * WN + ni * 16 + lr;
      float bs;
      if constexpr (SPLIT)
        bs = (col < 256) ? bias[col] : bias2[col - 256];
      else
        bs = bias[col];
      int row = m0 + wm * 64 + mi * 16 + lk * 4;
#pragma unroll
      for (int r = 0; r < 4; ++r) {
        float v = acc[mi][ni][r] + bs;
        if constexpr (SPLIT) {
          if (col < 256)
            ((ushort*)Cout)[(size_t)(row + r) * 256 + col] = h16(v);
          else
            C2[(size_t)(row + r) * 128 + col - 256] = h16(v);
        } else if constexpr (VT) {
          int rr = row + r;
          int bb = (rr >= LQ) ? 1 : 0;
          int pos = rr - bb * LQ;
          size_t idx =
              ((size_t)(bb * 8 + (col >> 5)) * LQ + pos) * 32 + (col & 31);
          ((ushort*)Cout)[idx] = h16(v);
        } else if constexpr (std::is_same_v<OT, ushort>) {
          Cout[(size_t)(row + r) * ldc + col] = h16(v);
        } else {
          Cout[(size_t)(row + r) * ldc + col] = v;
        }
      }
    }
  }
}

// ---- front: blocks 0..339 -> value GEMM, 340..679 -> offsets+logits GEMM ---
__global__ __launch_bounds__(512) void gemm_front(
    const float* __restrict__ inpf, const ushort* __restrict__ WTv,
    const float* __restrict__ bval, ushort* __restrict__ value16,
    const float* __restrict__ query, const ushort* __restrict__ WTol,
    const float* __restrict__ boff, const float* __restrict__ battn,
    ushort* __restrict__ off16, ushort* __restrict__ logit16) {
  __shared__ ushort Asb[2 * 128 * 32];
  __shared__ ushort Bsb[2 * 384 * 32];
  int bid = blockIdx.x;
  if (bid < 340) {
    gemm_body<256, false, true, float, ushort>(
        inpf, 256, WTv, bval, nullptr, value16, 256, nullptr, bid, Asb, Bsb);
  } else {
    gemm_body<384, true, false, float, ushort>(query, 256, WTol, boff, battn,
                                               off16, 256, logit16, bid - 340,
                                               Asb, Bsb);
  }
}

__global__ __launch_bounds__(512) void gemm_out(
    const ushort* __restrict__ midb, const ushort* __restrict__ WTu,
    const float* __restrict__ bout, float* __restrict__ outp) {
  __shared__ ushort Asb[2 * 128 * 32];
  __shared__ ushort Bsb[2 * 256 * 32];
  gemm_body<256, false, false, ushort, float>(midb, 512, WTu, bout, nullptr,
                                              outp, 256, nullptr, blockIdx.x,
                                              Asb, Bsb);
}

// -------- prep: all weight transposes (f32 [K][N] -> f16 [N][256]) ----------
__global__ __launch_bounds__(256) void wt_cvt_all(
    const float* __restrict__ Wval, const float* __restrict__ Woff,
    const float* __restrict__ Wattn, const float* __restrict__ Wout,
    ushort* __restrict__ WTv, ushort* __restrict__ WTol,
    ushort* __restrict__ WTu) {
  int i = blockIdx.x * 256 + threadIdx.x;  // < 229376
  if (i < 65536) {
    int n = i >> 8, k = i & 255;
    WTv[i] = h16(Wval[(size_t)k * 256 + n]);
  } else if (i < 163840) {
    int j = i - 65536;
    int n = j >> 8, k = j & 255;
    float s = (n < 256) ? Woff[(size_t)k * 256 + n] : Wattn[(size_t)k * 128 + n - 256];
    WTol[j] = h16(s);
  } else {
    int j = i - 163840;
    int n = j >> 8, k = j & 255;
    WTu[j] = h16(Wout[(size_t)k * 256 + n]);
  }
}

// ------------- sampler: XCD-pinned (batch, head-pair) groups ----------------
// (byte-identical to round-7: measured 68.4 us, at the empirical ~21 TB/s
// random-access L2 byte ceiling — two independent layouts converge there.)
// Negative-results ledger, do NOT revisit: explicit SW load pipelines (r1/r2:
// VGPR clamp + serialize), LDS-shrink occupancy (r5), level-major order (r4),
// pure-VALU cuts (r3: time invariant). Request-halving (r7): +2.5 us only ->
// byte-rate-bound, not request-bound.
__global__ __launch_bounds__(256) void msda_sample(
    const ushort* __restrict__ off16,   // [M][256] f16
    const ushort* __restrict__ logit16, // [M][128] f16
    const float* __restrict__ refpts,   // [M][4][2]
    const ushort* __restrict__ value,   // [B][8][LQ][32] f16 (head-major)
    ushort* __restrict__ midb) {        // f16, row r at midb + r*512
  __shared__ float prs[64][16];   // 4 KB
  __shared__ float refs[32][4][2];
  __shared__ int tix[1024][4];    // 16 KB ([2],[3] unused: occupancy pad)
  __shared__ uint twp[1024][2];   // 8 KB

  const int bid = blockIdx.x;
  const int grp = bid & 7;        // -> XCD (round-robin dispatch assumption)
  const int sub = bid >> 3;       // 0..679
  const int b = grp >> 2;
  const int hp = grp & 3;         // head pair: heads 2hp, 2hp+1
  const int q0 = sub * 32;
  const int tid = threadIdx.x;
  const size_t fqB = (size_t)b * LQ + q0;

  // ---- A0: refs (32q x 8 vals, 1/thread) + softmax for 64 (q, h') pairs ----
  {
    int q = tid >> 3, r = tid & 7;
    refs[q][r >> 1][r & 1] = refpts[(fqB + q) * 8 + r];
  }
  if (tid < 64) {
    int q = tid >> 1, hh = tid & 1;
    int h = hp * 2 + hh;
    const uint4* lp = (const uint4*)(logit16 + (fqB + q) * 128 + h * 16);
    uint4 p0 = lp[0], p1 = lp[1];
    float v[16] = {hlo(p0.x), hhi(p0.x), hlo(p0.y), hhi(p0.y),
                   hlo(p0.z), hhi(p0.z), hlo(p0.w), hhi(p0.w),
                   hlo(p1.x), hhi(p1.x), hlo(p1.y), hhi(p1.y),
                   hlo(p1.z), hhi(p1.z), hlo(p1.w), hhi(p1.w)};
    float m = v[0];
#pragma unroll
    for (int i = 1; i < 16; ++i) m = fmaxf(m, v[i]);
    float s = 0.f;
#pragma unroll
    for (int i = 0; i < 16; ++i) { v[i] = __expf(v[i] - m); s += v[i]; }
    float inv = 1.0f / s;
#pragma unroll
    for (int i = 0; i < 16; ++i) prs[tid][i] = v[i] * inv;
  }
  __syncthreads();

  // ---- A2: 1024 tasks (q 0..31, h' 0..1, lp 0..15), 4 per thread ----
#pragma unroll
  for (int i = 0; i < 4; ++i) {
    int t = tid + i * 256;
    int q = t >> 5;
    int hh = (t >> 4) & 1;
    int lp_ = t & 15;
    int lvl = lp_ >> 2;
    int h = hp * 2 + hh;
    uint op = ((const uint*)off16)[(fqB + q) * 128 + h * 16 + lp_];
    float ox = hlo(op), oy = hhi(op);
    float aw = prs[q * 2 + hh][lp_];
    float rx = refs[q][lvl][0], ry = refs[q][lvl][1];
    int Wl = 128 >> lvl;
    int st = (lvl == 0) ? 0 : ((lvl == 1) ? 16384 : ((lvl == 2) ? 20480 : 21504));
    float fW = (float)Wl;
    float invW = 1.0f / fW;
    float x = (rx + ox * invW) * fW - 0.5f;
    float y = (ry + oy * invW) * fW - 0.5f;
    float x0f = floorf(x), y0f = floorf(y);
    float wx1 = x - x0f, wy1 = y - y0f;
    float wx0 = 1.f - wx1, wy0 = 1.f - wy1;
    int x0 = (int)x0f, y0 = (int)y0f;
    int x1 = x0 + 1, y1 = y0 + 1;
    bool vx0 = (x0 >= 0) & (x0 < Wl), vx1 = (x1 >= 0) & (x1 < Wl);
    bool vy0 = (y0 >= 0) & (y0 < Wl), vy1 = (y1 >= 0) & (y1 < Wl);
    int xc0 = min(max(x0, 0), Wl - 1);
    int yc0 = min(max(y0, 0), Wl - 1), yc1 = min(max(y1, 0), Wl - 1);
    float w00 = (vx0 && vy0) ? wx0 * wy0 * aw : 0.f;
    float w10 = (vx1 && vy0) ? wx1 * wy0 * aw : 0.f;
    float w01 = (vx0 && vy1) ? wx0 * wy1 * aw : 0.f;
    float w11 = (vx1 && vy1) ? wx1 * wy1 * aw : 0.f;
    // weight swap: if x0<0, pixel xc0(=0) IS the x1 corner -> lo slot = w10
    bool xs = (x0 < 0);
    float lo0 = xs ? w10 : w00, hi0 = xs ? 0.f : w10;
    float lo1 = xs ? w11 : w01, hi1 = xs ? 0.f : w11;
    // head-major byte offsets: pixel stride 64 B, x-pair contiguous 128 B
    int baseB = (h * LQ + st + yc0 * Wl + xc0) * 64;
    int dyB = (yc1 - yc0) * Wl * 64;
    // stagger keyed by GATHER group (qh>>1 = t>>5) so reads walk distinct rows
    int slot = (t & ~15) | ((lp_ + (t >> 5)) & 15);
    tix[slot][0] = baseB;
    tix[slot][1] = dyB;
    twp[slot][0] = pkh(lo0, hi0);
    twp[slot][1] = pkh(lo1, hi1);
  }
  __syncthreads();

  // ---- B: gather. 8 lanes per (q,h'); lanes<4 own x0 dims, lanes>=4 x1 ----
  const int g8 = tid >> 3;        // 32 groups
  const int dl = tid & 7;
  const uint dlB = (uint)dl * 16u;          // covers the 128B x-pair
  const uint sh = (uint)((tid & 4) << 2);   // 0 (lo weight) / 16 (hi weight)
  const char* vb0c = (const char*)(value + (size_t)b * (LEN * 256));

// packed f16 FMA, weight word pre-shifted so lo half is always the weight;
// op_sel broadcasts weight.lo to both halves.
#define PKC(ACC, U, WP)                                                 \
  asm("v_pk_fma_f16 %0, %1, %2, %0 op_sel:[0,0,0] op_sel_hi:[1,0,1]"    \
      : "+v"(ACC)                                                       \
      : "v"(U), "v"(WP))
// promote f16x2 chunk into two f32 accumulators, then reset chunk
#define PROMO1(ALO, AHI, C)                                             \
  asm("v_fma_mix_f32 %0, 1.0, %1, %0 op_sel:[0,0,0] op_sel_hi:[0,1,0]"  \
      : "+v"(ALO) : "v"(C));                                            \
  asm("v_fma_mix_f32 %0, 1.0, %1, %0 op_sel:[0,1,0] op_sel_hi:[0,1,0]"  \
      : "+v"(AHI) : "v"(C));                                            \
  C = 0u;

#pragma unroll
  for (int half = 0; half < 2; ++half) {
    const int qh = g8 * 2 + half;
    const int tb2 = qh * 16;
    float a0 = 0.f, a1 = 0.f, a2 = 0.f, a3 = 0.f;
    float a4 = 0.f, a5 = 0.f, a6 = 0.f, a7 = 0.f;
    uint c0 = 0u, c1 = 0u, c2 = 0u, c3 = 0u;
#pragma unroll 4
    for (int t = 0; t < 16; ++t) {
      int slot = tb2 + ((t + g8) & 15);
      int2 bx = *(const int2*)&tix[slot][0];
      uint2 wp = *(const uint2*)&twp[slot][0];
      const char* p0 = vb0c + (uint)bx.x + dlB;
      uint4 u0 = *(const uint4*)p0;
      uint4 u1 = *(const uint4*)(p0 + (uint)bx.y);
      uint wp0 = wp.x >> sh;
      uint wp1 = wp.y >> sh;
      PKC(c0, u0.x, wp0); PKC(c1, u0.y, wp0);
      PKC(c2, u0.z, wp0); PKC(c3, u0.w, wp0);
      PKC(c0, u1.x, wp1); PKC(c1, u1.y, wp1);
      PKC(c2, u1.z, wp1); PKC(c3, u1.w, wp1);
      if ((t & 3) == 3) {  // promote every 4 tasks (8 f16 contributions)
        PROMO1(a0, a1, c0);
        PROMO1(a2, a3, c1);
        PROMO1(a4, a5, c2);
        PROMO1(a6, a7, c3);
      }
    }
    // combine x0/x1 partials across the 8-lane group
    a0 += __shfl_xor(a0, 4); a1 += __shfl_xor(a1, 4);
    a2 += __shfl_xor(a2, 4); a3 += __shfl_xor(a3, 4);
    a4 += __shfl_xor(a4, 4); a5 += __shfl_xor(a5, 4);
    a6 += __shfl_xor(a6, 4); a7 += __shfl_xor(a7, 4);
    if (dl < 4) {
      const int q = qh >> 1, h = hp * 2 + (qh & 1);
      ushort* mp = midb + (fqB + q) * 512 + h * 32 + dl * 8;
      *(uint4*)mp =
          make_uint4(pkh(a0, a1), pkh(a2, a3), pkh(a4, a5), pkh(a6, a7));
    }
  }
#undef PROMO1
#undef PKC
}

extern "C" void kernel_launch(void* const* d_in, const int* in_sizes, int n_in,
                              void* d_out, int out_size, void* d_ws,
                              size_t ws_size, hipStream_t stream) {
  (void)in_sizes; (void)n_in; (void)out_size; (void)ws_size;
  const float* query = (const float*)d_in[0];
  const float* refp  = (const float*)d_in[1];
  const float* inpf  = (const float*)d_in[2];
  const float* Woff  = (const float*)d_in[5];
  const float* boff  = (const float*)d_in[6];
  const float* Wattn = (const float*)d_in[7];
  const float* battn = (const float*)d_in[8];
  const float* Wval  = (const float*)d_in[9];
  const float* bval  = (const float*)d_in[10];
  const float* Wout  = (const float*)d_in[11];
  const float* bout  = (const float*)d_in[12];

  // ws: value16 22.3MB | off16 22.3MB | logit16 11.1MB | WT f16 ~0.45MB
  ushort* value16 = (ushort*)d_ws;
  ushort* off16   = value16 + (size_t)MROWS * 256;
  ushort* logit16 = off16 + (size_t)MROWS * 256;
  ushort* WTv     = logit16 + (size_t)MROWS * 128;
  ushort* WTol    = WTv + 65536;   // [384][256]
  ushort* WTu     = WTol + 98304;

  ushort* midb = (ushort*)d_out;   // mid f16 in-place per row (stride 512)

  wt_cvt_all<<<896, 256, 0, stream>>>(Wval, Woff, Wattn, Wout, WTv, WTol, WTu);

  gemm_front<<<680, 512, 0, stream>>>(inpf, WTv, bval, value16, query, WTol,
                                      boff, battn, off16, logit16);

  msda_sample<<<MROWS / 8, 256, 0, stream>>>(off16, logit16, refp, value16,
                                             midb);

  gemm_out<<<MROWS / 128, 512, 0, stream>>>(midb, WTu, bout, (float*)d_out);
}